// Round 1
// baseline (5821.302 us; speedup 1.0000x reference)
//
#include <hip/hip_runtime.h>

#define NN 50000
#define NE 800000
#define NH 128
#define NO 64
#define NL 4
#define BN_EPS 1e-5f

// ---------- degree / norm precompute ----------
__global__ void k_deg(const int* __restrict__ dst, float* __restrict__ deg) {
    int e = blockIdx.x * 256 + threadIdx.x;
    if (e < NE) atomicAdd(&deg[dst[e]], 1.0f);
}

__global__ void k_dinv(float* deg) {
    int i = blockIdx.x * 256 + threadIdx.x;
    if (i < NN) deg[i] = rsqrtf(deg[i] + 1.0f);  // +1 for self loop; always >= 1
}

__global__ void k_norm(const int* __restrict__ src, const int* __restrict__ dst,
                       const float* __restrict__ dinv, float* __restrict__ norm) {
    int e = blockIdx.x * 256 + threadIdx.x;
    if (e < NE) norm[e] = dinv[src[e]] * dinv[dst[e]];
}

// ---------- GEMM: H = X @ W   (X: [NN,128], W: [128,128]) ----------
__global__ __launch_bounds__(256) void k_gemm_xw(const float* __restrict__ X,
                                                 const float* __restrict__ W,
                                                 float* __restrict__ H) {
    __shared__ float xs[32][128];
    int tid = threadIdx.x;
    int row0 = blockIdx.x * 32;
    for (int i = tid; i < 32 * 128; i += 256) {
        int r = i >> 7, c = i & 127;
        int gr = row0 + r;
        xs[r][c] = (gr < NN) ? X[(long long)gr * NH + c] : 0.0f;
    }
    __syncthreads();
    int col = tid & 127;
    int rb = (tid >> 7) * 16;
    float acc[16];
#pragma unroll
    for (int i = 0; i < 16; i++) acc[i] = 0.0f;
    for (int k = 0; k < NH; k += 4) {
        float w0 = W[(k + 0) * NH + col];
        float w1 = W[(k + 1) * NH + col];
        float w2 = W[(k + 2) * NH + col];
        float w3 = W[(k + 3) * NH + col];
#pragma unroll
        for (int i = 0; i < 16; i++) {
            float4 xv = *(const float4*)&xs[rb + i][k];
            acc[i] = fmaf(xv.x, w0, fmaf(xv.y, w1, fmaf(xv.z, w2, fmaf(xv.w, w3, acc[i]))));
        }
    }
#pragma unroll
    for (int i = 0; i < 16; i++) {
        int gr = row0 + rb + i;
        if (gr < NN) H[(long long)gr * NH + col] = acc[i];
    }
}

// ---------- AGG init with self-loop term: AGG = H * dinv^2 ----------
__global__ void k_agg_init(const float* __restrict__ H, const float* __restrict__ dinv,
                           float* __restrict__ agg) {
    int i4 = blockIdx.x * 256 + threadIdx.x;
    if (i4 >= NN * NH / 4) return;
    float dv = dinv[i4 >> 5];           // 32 float4 per row
    float s = dv * dv;
    float4 h = ((const float4*)H)[i4];
    float4 o;
    o.x = h.x * s; o.y = h.y * s; o.z = h.z * s; o.w = h.w * s;
    ((float4*)agg)[i4] = o;
}

// ---------- edge scatter: AGG[dst] += H[src] * norm ----------
__global__ __launch_bounds__(256) void k_scatter(const float* __restrict__ H,
                                                 const int* __restrict__ src,
                                                 const int* __restrict__ dst,
                                                 const float* __restrict__ norm,
                                                 float* __restrict__ agg) {
    long long gid = (long long)blockIdx.x * 256 + threadIdx.x;
    int e = (int)(gid >> 5);
    if (e >= NE) return;
    int q = ((int)gid & 31) * 4;
    int s = src[e], d = dst[e];
    float nm = norm[e];
    float4 hv = *(const float4*)&H[(long long)s * NH + q];
    float* a = &agg[(long long)d * NH + q];
    atomicAdd(a + 0, hv.x * nm);
    atomicAdd(a + 1, hv.y * nm);
    atomicAdd(a + 2, hv.z * nm);
    atomicAdd(a + 3, hv.w * nm);
}

// ---------- BN column stats ----------
__global__ __launch_bounds__(256) void k_bn_stats(const float* __restrict__ agg,
                                                  float* __restrict__ sums,
                                                  float* __restrict__ sumsq) {
    int tid = threadIdx.x;
    int col = tid & 127;
    float s = 0.0f, s2 = 0.0f;
    for (int r = blockIdx.x * 2 + (tid >> 7); r < NN; r += gridDim.x * 2) {
        float v = agg[(long long)r * NH + col];
        s += v;
        s2 = fmaf(v, v, s2);
    }
    __shared__ float ls[256], ls2[256];
    ls[tid] = s; ls2[tid] = s2;
    __syncthreads();
    if (tid < 128) {
        atomicAdd(&sums[col], ls[tid] + ls[tid + 128]);
        atomicAdd(&sumsq[col], ls2[tid] + ls2[tid + 128]);
    }
}

__global__ void k_bn_fin(const float* __restrict__ sums, const float* __restrict__ sumsq,
                         const float* __restrict__ gamma, const float* __restrict__ beta,
                         float* __restrict__ scale, float* __restrict__ shift) {
    int c = threadIdx.x;
    if (c < NH) {
        float mean = sums[c] * (1.0f / NN);
        float var = sumsq[c] * (1.0f / NN) - mean * mean;
        float istd = rsqrtf(var + BN_EPS);
        float sc = istd * gamma[c];
        scale[c] = sc;
        shift[c] = beta[c] - mean * sc;
    }
}

// ---------- BN apply + ReLU + residual ----------
__global__ void k_elem(const float* __restrict__ agg, const float* __restrict__ scale,
                       const float* __restrict__ shift, const float* __restrict__ prev,
                       float* __restrict__ X) {
    int i4 = blockIdx.x * 256 + threadIdx.x;
    if (i4 >= NN * NH / 4) return;
    int c4 = i4 & 31;
    float4 a = ((const float4*)agg)[i4];
    float4 sc = ((const float4*)scale)[c4];
    float4 sh = ((const float4*)shift)[c4];
    float4 p = ((const float4*)prev)[i4];
    float4 o;
    o.x = fmaxf(fmaf(a.x, sc.x, sh.x), 0.0f) + p.x;
    o.y = fmaxf(fmaf(a.y, sc.y, sh.y), 0.0f) + p.y;
    o.z = fmaxf(fmaf(a.z, sc.z, sh.z), 0.0f) + p.z;
    o.w = fmaxf(fmaf(a.w, sc.w, sh.w), 0.0f) + p.w;
    ((float4*)X)[i4] = o;
}

// ---------- output GEMM: out = X @ Wout + bout  (Wout: [128,64]) ----------
__global__ __launch_bounds__(256) void k_gemm_out(const float* __restrict__ X,
                                                  const float* __restrict__ W,
                                                  const float* __restrict__ b,
                                                  float* __restrict__ out) {
    __shared__ float xs[32][128];
    int tid = threadIdx.x;
    int row0 = blockIdx.x * 32;
    for (int i = tid; i < 32 * 128; i += 256) {
        int r = i >> 7, c = i & 127;
        int gr = row0 + r;
        xs[r][c] = (gr < NN) ? X[(long long)gr * NH + c] : 0.0f;
    }
    __syncthreads();
    int col = tid & 63;
    int rb = (tid >> 6) * 8;
    float acc[8];
#pragma unroll
    for (int i = 0; i < 8; i++) acc[i] = 0.0f;
    for (int k = 0; k < NH; k += 4) {
        float w0 = W[(k + 0) * NO + col];
        float w1 = W[(k + 1) * NO + col];
        float w2 = W[(k + 2) * NO + col];
        float w3 = W[(k + 3) * NO + col];
#pragma unroll
        for (int i = 0; i < 8; i++) {
            float4 xv = *(const float4*)&xs[rb + i][k];
            acc[i] = fmaf(xv.x, w0, fmaf(xv.y, w1, fmaf(xv.z, w2, fmaf(xv.w, w3, acc[i]))));
        }
    }
    float bb = b[col];
#pragma unroll
    for (int i = 0; i < 8; i++) {
        int gr = row0 + rb + i;
        if (gr < NN) out[(long long)gr * NO + col] = acc[i] + bb;
    }
}

extern "C" void kernel_launch(void* const* d_in, const int* in_sizes, int n_in,
                              void* d_out, int out_size, void* d_ws, size_t ws_size,
                              hipStream_t stream) {
    const float* x    = (const float*)d_in[0];
    const int*   ei   = (const int*)d_in[1];
    const float* Ws   = (const float*)d_in[2];
    const float* gam  = (const float*)d_in[4];
    const float* bet  = (const float*)d_in[5];
    const float* Wout = (const float*)d_in[6];
    const float* bout = (const float*)d_in[7];
    float* out = (float*)d_out;

    const int* src = ei;
    const int* dst = ei + NE;

    float* ws    = (float*)d_ws;
    float* dinv  = ws;                     // NN (padded to 50176)
    float* norm  = dinv + 50176;           // NE
    float* X     = norm + NE;              // NN*NH
    float* H     = X + (size_t)NN * NH;    // NN*NH
    float* AGG   = H + (size_t)NN * NH;    // NN*NH
    float* sums  = AGG + (size_t)NN * NH;  // 128
    float* sumsq = sums + NH;              // 128
    float* scale = sumsq + NH;             // 128
    float* shift = scale + NH;             // 128

    hipMemsetAsync(dinv, 0, NN * sizeof(float), stream);
    k_deg<<<(NE + 255) / 256, 256, 0, stream>>>(dst, dinv);
    k_dinv<<<(NN + 255) / 256, 256, 0, stream>>>(dinv);
    k_norm<<<(NE + 255) / 256, 256, 0, stream>>>(src, dst, dinv, norm);

    const float* xcur = x;
    for (int l = 0; l < NL; l++) {
        k_gemm_xw<<<(NN + 31) / 32, 256, 0, stream>>>(xcur, Ws + (size_t)l * NH * NH, H);
        k_agg_init<<<(NN * NH / 4 + 255) / 256, 256, 0, stream>>>(H, dinv, AGG);
        k_scatter<<<(int)(((long long)NE * 32 + 255) / 256), 256, 0, stream>>>(H, src, dst, norm, AGG);
        hipMemsetAsync(sums, 0, 2 * NH * sizeof(float), stream);
        k_bn_stats<<<512, 256, 0, stream>>>(AGG, sums, sumsq);
        k_bn_fin<<<1, 128, 0, stream>>>(sums, sumsq, gam + l * NH, bet + l * NH, scale, shift);
        k_elem<<<(NN * NH / 4 + 255) / 256, 256, 0, stream>>>(AGG, scale, shift, xcur, X);
        xcur = X;
    }
    k_gemm_out<<<(NN + 31) / 32, 256, 0, stream>>>(X, Wout, bout, out);
}

// Round 2
// 733.711 us; speedup vs baseline: 7.9341x; 7.9341x over previous
//
#include <hip/hip_runtime.h>

#define NN 50000
#define NE 800000
#define NH 128
#define NO 64
#define NL 4
#define BN_EPS 1e-5f
#define NB1 ((NN + 255) / 256)   // 196 scan blocks

// ---------- degree count (int atomics) ----------
__global__ void k_deg(const int* __restrict__ dst, int* __restrict__ deg) {
    int e = blockIdx.x * 256 + threadIdx.x;
    if (e < NE) atomicAdd(&deg[e < NE ? dst[e] : 0], 1);
}

__global__ void k_dinv(const int* __restrict__ deg, float* __restrict__ dinv) {
    int i = blockIdx.x * 256 + threadIdx.x;
    if (i < NN) dinv[i] = rsqrtf((float)deg[i] + 1.0f);  // +1 self loop
}

// ---------- 3-phase exclusive scan of deg -> off ----------
__global__ void k_scan1(const int* __restrict__ deg, int* __restrict__ off, int* __restrict__ aux) {
    __shared__ int ls[256];
    int i = blockIdx.x * 256 + threadIdx.x;
    int v = (i < NN) ? deg[i] : 0;
    ls[threadIdx.x] = v;
    __syncthreads();
    for (int s = 1; s < 256; s <<= 1) {
        int t = (threadIdx.x >= s) ? ls[threadIdx.x - s] : 0;
        __syncthreads();
        ls[threadIdx.x] += t;
        __syncthreads();
    }
    if (i < NN) off[i] = ls[threadIdx.x] - v;  // exclusive
    if (threadIdx.x == 255) aux[blockIdx.x] = ls[255];
}

__global__ void k_scan2(int* __restrict__ aux) {
    __shared__ int ls[256];
    int v = (threadIdx.x < NB1) ? aux[threadIdx.x] : 0;
    ls[threadIdx.x] = v;
    __syncthreads();
    for (int s = 1; s < 256; s <<= 1) {
        int t = (threadIdx.x >= s) ? ls[threadIdx.x - s] : 0;
        __syncthreads();
        ls[threadIdx.x] += t;
        __syncthreads();
    }
    if (threadIdx.x < NB1) aux[threadIdx.x] = ls[threadIdx.x] - v;  // exclusive block offsets
}

__global__ void k_scan3(int* __restrict__ off, const int* __restrict__ aux) {
    int i = blockIdx.x * 256 + threadIdx.x;
    if (i < NN) off[i] += aux[blockIdx.x];
}

// ---------- CSR fill ----------
__global__ void k_fill(const int* __restrict__ src, const int* __restrict__ dst,
                       const int* __restrict__ off, int* __restrict__ cur,
                       int* __restrict__ csr) {
    int e = blockIdx.x * 256 + threadIdx.x;
    if (e < NE) {
        int d = dst[e];
        int p = off[d] + atomicAdd(&cur[d], 1);
        csr[p] = src[e];
    }
}

// ---------- GEMM: Hd = (X @ W) * dinv[row] ----------
__global__ __launch_bounds__(256) void k_gemm_xw(const float* __restrict__ X,
                                                 const float* __restrict__ W,
                                                 const float* __restrict__ dinv,
                                                 float* __restrict__ Hd) {
    __shared__ float xs[32][128];
    int tid = threadIdx.x;
    int row0 = blockIdx.x * 32;
    for (int i = tid; i < 32 * 128; i += 256) {
        int r = i >> 7, c = i & 127;
        int gr = row0 + r;
        xs[r][c] = (gr < NN) ? X[(long long)gr * NH + c] : 0.0f;
    }
    __syncthreads();
    int col = tid & 127;
    int rb = (tid >> 7) * 16;
    float acc[16];
#pragma unroll
    for (int i = 0; i < 16; i++) acc[i] = 0.0f;
    for (int k = 0; k < NH; k += 4) {
        float w0 = W[(k + 0) * NH + col];
        float w1 = W[(k + 1) * NH + col];
        float w2 = W[(k + 2) * NH + col];
        float w3 = W[(k + 3) * NH + col];
#pragma unroll
        for (int i = 0; i < 16; i++) {
            float4 xv = *(const float4*)&xs[rb + i][k];
            acc[i] = fmaf(xv.x, w0, fmaf(xv.y, w1, fmaf(xv.z, w2, fmaf(xv.w, w3, acc[i]))));
        }
    }
#pragma unroll
    for (int i = 0; i < 16; i++) {
        int gr = row0 + rb + i;
        if (gr < NN) Hd[(long long)gr * NH + col] = acc[i] * dinv[gr];
    }
}

// ---------- CSR gather: agg[d] = dinv[d] * (Hd[d] + sum_e Hd[src_e]) ----------
__global__ __launch_bounds__(256) void k_gather(const float* __restrict__ Hd,
                                                const int* __restrict__ csr,
                                                const int* __restrict__ off,
                                                const int* __restrict__ deg,
                                                const float* __restrict__ dinv,
                                                float* __restrict__ agg) {
    int node = blockIdx.x * 8 + (threadIdx.x >> 5);
    if (node >= NN) return;
    int lane = threadIdx.x & 31;
    int o = off[node];
    int d = deg[node];
    float4 acc = ((const float4*)Hd)[(long long)node * 32 + lane];  // self term
    for (int j = 0; j < d; j++) {
        int s = csr[o + j];
        float4 h = ((const float4*)Hd)[(long long)s * 32 + lane];
        acc.x += h.x; acc.y += h.y; acc.z += h.z; acc.w += h.w;
    }
    float dv = dinv[node];
    acc.x *= dv; acc.y *= dv; acc.z *= dv; acc.w *= dv;
    ((float4*)agg)[(long long)node * 32 + lane] = acc;
}

// ---------- BN column stats ----------
__global__ __launch_bounds__(256) void k_bn_stats(const float* __restrict__ agg,
                                                  float* __restrict__ sums,
                                                  float* __restrict__ sumsq) {
    int tid = threadIdx.x;
    int col = tid & 127;
    float s = 0.0f, s2 = 0.0f;
    for (int r = blockIdx.x * 2 + (tid >> 7); r < NN; r += gridDim.x * 2) {
        float v = agg[(long long)r * NH + col];
        s += v;
        s2 = fmaf(v, v, s2);
    }
    __shared__ float ls[256], ls2[256];
    ls[tid] = s; ls2[tid] = s2;
    __syncthreads();
    if (tid < 128) {
        atomicAdd(&sums[col], ls[tid] + ls[tid + 128]);
        atomicAdd(&sumsq[col], ls2[tid] + ls2[tid + 128]);
    }
}

__global__ void k_bn_fin(const float* __restrict__ sums, const float* __restrict__ sumsq,
                         const float* __restrict__ gamma, const float* __restrict__ beta,
                         float* __restrict__ scale, float* __restrict__ shift) {
    int c = threadIdx.x;
    if (c < NH) {
        float mean = sums[c] * (1.0f / NN);
        float var = sumsq[c] * (1.0f / NN) - mean * mean;
        float istd = rsqrtf(var + BN_EPS);
        float sc = istd * gamma[c];
        scale[c] = sc;
        shift[c] = beta[c] - mean * sc;
    }
}

// ---------- BN apply + ReLU + residual (in-place on agg) ----------
__global__ void k_elem(const float* __restrict__ agg, const float* __restrict__ scale,
                       const float* __restrict__ shift, const float* __restrict__ prev,
                       float* __restrict__ X) {
    int i4 = blockIdx.x * 256 + threadIdx.x;
    if (i4 >= NN * NH / 4) return;
    int c4 = i4 & 31;
    float4 a = ((const float4*)agg)[i4];
    float4 sc = ((const float4*)scale)[c4];
    float4 sh = ((const float4*)shift)[c4];
    float4 p = ((const float4*)prev)[i4];
    float4 o;
    o.x = fmaxf(fmaf(a.x, sc.x, sh.x), 0.0f) + p.x;
    o.y = fmaxf(fmaf(a.y, sc.y, sh.y), 0.0f) + p.y;
    o.z = fmaxf(fmaf(a.z, sc.z, sh.z), 0.0f) + p.z;
    o.w = fmaxf(fmaf(a.w, sc.w, sh.w), 0.0f) + p.w;
    ((float4*)X)[i4] = o;
}

// ---------- output GEMM: out = X @ Wout + bout ----------
__global__ __launch_bounds__(256) void k_gemm_out(const float* __restrict__ X,
                                                  const float* __restrict__ W,
                                                  const float* __restrict__ b,
                                                  float* __restrict__ out) {
    __shared__ float xs[32][128];
    int tid = threadIdx.x;
    int row0 = blockIdx.x * 32;
    for (int i = tid; i < 32 * 128; i += 256) {
        int r = i >> 7, c = i & 127;
        int gr = row0 + r;
        xs[r][c] = (gr < NN) ? X[(long long)gr * NH + c] : 0.0f;
    }
    __syncthreads();
    int col = tid & 63;
    int rb = (tid >> 6) * 8;
    float acc[8];
#pragma unroll
    for (int i = 0; i < 8; i++) acc[i] = 0.0f;
    for (int k = 0; k < NH; k += 4) {
        float w0 = W[(k + 0) * NO + col];
        float w1 = W[(k + 1) * NO + col];
        float w2 = W[(k + 2) * NO + col];
        float w3 = W[(k + 3) * NO + col];
#pragma unroll
        for (int i = 0; i < 8; i++) {
            float4 xv = *(const float4*)&xs[rb + i][k];
            acc[i] = fmaf(xv.x, w0, fmaf(xv.y, w1, fmaf(xv.z, w2, fmaf(xv.w, w3, acc[i]))));
        }
    }
    float bb = b[col];
#pragma unroll
    for (int i = 0; i < 8; i++) {
        int gr = row0 + rb + i;
        if (gr < NN) out[(long long)gr * NO + col] = acc[i] + bb;
    }
}

extern "C" void kernel_launch(void* const* d_in, const int* in_sizes, int n_in,
                              void* d_out, int out_size, void* d_ws, size_t ws_size,
                              hipStream_t stream) {
    const float* x    = (const float*)d_in[0];
    const int*   ei   = (const int*)d_in[1];
    const float* Ws   = (const float*)d_in[2];
    const float* gam  = (const float*)d_in[4];
    const float* bet  = (const float*)d_in[5];
    const float* Wout = (const float*)d_in[6];
    const float* bout = (const float*)d_in[7];
    float* out = (float*)d_out;

    const int* src = ei;
    const int* dst = ei + NE;

    // workspace carve-up (256B aligned)
    char* p = (char*)d_ws;
    auto alloc = [&](size_t bytes) { char* r = p; p += (bytes + 255) & ~(size_t)255; return r; };
    int*   deg_i = (int*)alloc(NN * 4);
    int*   off   = (int*)alloc(NN * 4);
    int*   cur   = (int*)alloc(NN * 4);
    int*   aux   = (int*)alloc(256 * 4);
    int*   csr   = (int*)alloc((size_t)NE * 4);
    float* dinv  = (float*)alloc(NN * 4);
    float* A     = (float*)alloc((size_t)NN * NH * 4);
    float* B     = (float*)alloc((size_t)NN * NH * 4);
    float* Hd    = (float*)alloc((size_t)NN * NH * 4);
    float* sums  = (float*)alloc(NH * 4);
    float* sumsq = (float*)alloc(NH * 4);
    float* scale = (float*)alloc(NH * 4);
    float* shift = (float*)alloc(NH * 4);

    // ---- graph preprocessing ----
    hipMemsetAsync(deg_i, 0, NN * 4, stream);
    hipMemsetAsync(cur, 0, NN * 4, stream);
    k_deg<<<(NE + 255) / 256, 256, 0, stream>>>(dst, deg_i);
    k_dinv<<<(NN + 255) / 256, 256, 0, stream>>>(deg_i, dinv);
    k_scan1<<<NB1, 256, 0, stream>>>(deg_i, off, aux);
    k_scan2<<<1, 256, 0, stream>>>(aux);
    k_scan3<<<NB1, 256, 0, stream>>>(off, aux);
    k_fill<<<(NE + 255) / 256, 256, 0, stream>>>(src, dst, off, cur, csr);

    // ---- layers (ping-pong A/B; xcur = residual input) ----
    const float* xcur = x;
    for (int l = 0; l < NL; l++) {
        float* AGG = (l & 1) ? B : A;
        k_gemm_xw<<<(NN + 31) / 32, 256, 0, stream>>>(xcur, Ws + (size_t)l * NH * NH, dinv, Hd);
        k_gather<<<(NN + 7) / 8, 256, 0, stream>>>(Hd, csr, off, deg_i, dinv, AGG);
        hipMemsetAsync(sums, 0, 2 * NH * sizeof(float), stream);
        k_bn_stats<<<512, 256, 0, stream>>>(AGG, sums, sumsq);
        k_bn_fin<<<1, 128, 0, stream>>>(sums, sumsq, gam + l * NH, bet + l * NH, scale, shift);
        k_elem<<<(NN * NH / 4 + 255) / 256, 256, 0, stream>>>(AGG, scale, shift, xcur, AGG);
        xcur = AGG;
    }
    k_gemm_out<<<(NN + 31) / 32, 256, 0, stream>>>(xcur, Wout, bout, out);
}

// Round 3
// 486.304 us; speedup vs baseline: 11.9705x; 1.5087x over previous
//
#include <hip/hip_runtime.h>

#define NN 50000
#define NE 800000
#define NH 128
#define NO 64
#define NL 4
#define BN_EPS 1e-5f
#define NB1 ((NN + 255) / 256)   // 196 scan blocks

typedef __attribute__((ext_vector_type(8))) short short8;
typedef __attribute__((ext_vector_type(4))) float f32x4;

__device__ inline unsigned short f2bf(float f) {
    unsigned int u = __float_as_uint(f);
    return (unsigned short)((u + 0x7fffu + ((u >> 16) & 1u)) >> 16);
}
__device__ inline float bflo(unsigned int u) { return __uint_as_float(u << 16); }
__device__ inline float bfhi(unsigned int u) { return __uint_as_float(u & 0xffff0000u); }

// ---------- degree / norm precompute ----------
__global__ void k_deg(const int* __restrict__ dst, int* __restrict__ deg) {
    int e = blockIdx.x * 256 + threadIdx.x;
    if (e < NE) atomicAdd(&deg[dst[e]], 1);
}

__global__ void k_dinv(const int* __restrict__ deg, float* __restrict__ dinv) {
    int i = blockIdx.x * 256 + threadIdx.x;
    if (i < NN) dinv[i] = rsqrtf((float)deg[i] + 1.0f);  // +1 self loop
}

// ---------- 3-phase exclusive scan ----------
__global__ void k_scan1(const int* __restrict__ deg, int* __restrict__ off, int* __restrict__ aux) {
    __shared__ int ls[256];
    int i = blockIdx.x * 256 + threadIdx.x;
    int v = (i < NN) ? deg[i] : 0;
    ls[threadIdx.x] = v;
    __syncthreads();
    for (int s = 1; s < 256; s <<= 1) {
        int t = (threadIdx.x >= s) ? ls[threadIdx.x - s] : 0;
        __syncthreads();
        ls[threadIdx.x] += t;
        __syncthreads();
    }
    if (i < NN) off[i] = ls[threadIdx.x] - v;
    if (threadIdx.x == 255) aux[blockIdx.x] = ls[255];
}

__global__ void k_scan2(int* __restrict__ aux) {
    __shared__ int ls[256];
    int v = (threadIdx.x < NB1) ? aux[threadIdx.x] : 0;
    ls[threadIdx.x] = v;
    __syncthreads();
    for (int s = 1; s < 256; s <<= 1) {
        int t = (threadIdx.x >= s) ? ls[threadIdx.x - s] : 0;
        __syncthreads();
        ls[threadIdx.x] += t;
        __syncthreads();
    }
    if (threadIdx.x < NB1) aux[threadIdx.x] = ls[threadIdx.x] - v;
}

__global__ void k_scan3(int* __restrict__ off, const int* __restrict__ aux) {
    int i = blockIdx.x * 256 + threadIdx.x;
    if (i < NN) off[i] += aux[blockIdx.x];
}

// ---------- CSR fill ----------
__global__ void k_fill(const int* __restrict__ src, const int* __restrict__ dst,
                       const int* __restrict__ off, int* __restrict__ cur,
                       int* __restrict__ csr) {
    int e = blockIdx.x * 256 + threadIdx.x;
    if (e < NE) {
        int d = dst[e];
        int p = off[d] + atomicAdd(&cur[d], 1);
        csr[p] = src[e];
    }
}

// ---------- pack W [128][128] f32 -> MFMA B-fragment order, bf16 ----------
__global__ void k_packW(const float* __restrict__ Ws, unsigned short* __restrict__ Wpk) {
    int t = blockIdx.x * 256 + threadIdx.x;
    if (t >= NL * 16384) return;
    int l = t >> 14, r = t & 16383;
    int ks = r >> 12, ct = (r >> 9) & 7, lane = (r >> 3) & 63, i = r & 7;
    int k = ks * 32 + (lane >> 4) * 8 + i;
    int n = ct * 16 + (lane & 15);
    Wpk[t] = f2bf(Ws[l * 16384 + k * 128 + n]);
}

__global__ void k_packWout(const float* __restrict__ Wout, unsigned short* __restrict__ Wpk) {
    int r = blockIdx.x * 256 + threadIdx.x;
    if (r >= 8192) return;
    int ks = r >> 11, ct = (r >> 9) & 3, lane = (r >> 3) & 63, i = r & 7;
    int k = ks * 32 + (lane >> 4) * 8 + i;
    int n = ct * 16 + (lane & 15);
    Wpk[r] = f2bf(Wout[k * 64 + n]);
}

// ---------- f32 -> bf16 convert (initial x) ----------
__global__ void k_cvt(const float* __restrict__ x, unsigned short* __restrict__ Xb) {
    int i4 = blockIdx.x * 256 + threadIdx.x;
    if (i4 >= NN * 32) return;
    float4 v = ((const float4*)x)[i4];
    uint2 u;
    u.x = (unsigned)f2bf(v.x) | ((unsigned)f2bf(v.y) << 16);
    u.y = (unsigned)f2bf(v.z) | ((unsigned)f2bf(v.w) << 16);
    ((uint2*)Xb)[i4] = u;
}

// ---------- MFMA GEMM: Hd(bf16) = (Xb @ W) * dinv[row] ----------
__global__ __launch_bounds__(256) void k_gemm_mfma(const unsigned short* __restrict__ Xb,
                                                   const unsigned short* __restrict__ Wpk,
                                                   const float* __restrict__ dinv,
                                                   unsigned short* __restrict__ Hd) {
    int w = threadIdx.x >> 6, l = threadIdx.x & 63;
    int row0 = blockIdx.x * 64 + w * 16;
    int lo = l & 15, hi = l >> 4;
    int arow = row0 + lo; if (arow >= NN) arow = NN - 1;
    const short8* Xv = (const short8*)Xb;
    short8 a0 = Xv[arow * 16 + 0 + hi];
    short8 a1 = Xv[arow * 16 + 4 + hi];
    short8 a2 = Xv[arow * 16 + 8 + hi];
    short8 a3 = Xv[arow * 16 + 12 + hi];
    const short8* Wv = (const short8*)Wpk;
    int srow = row0 + hi * 4;
    float dv[4];
#pragma unroll
    for (int r = 0; r < 4; r++) dv[r] = (srow + r < NN) ? dinv[srow + r] : 0.0f;
#pragma unroll
    for (int ct = 0; ct < 8; ct++) {
        f32x4 acc = {0.0f, 0.0f, 0.0f, 0.0f};
        acc = __builtin_amdgcn_mfma_f32_16x16x32_bf16(a0, Wv[(0 * 8 + ct) * 64 + l], acc, 0, 0, 0);
        acc = __builtin_amdgcn_mfma_f32_16x16x32_bf16(a1, Wv[(1 * 8 + ct) * 64 + l], acc, 0, 0, 0);
        acc = __builtin_amdgcn_mfma_f32_16x16x32_bf16(a2, Wv[(2 * 8 + ct) * 64 + l], acc, 0, 0, 0);
        acc = __builtin_amdgcn_mfma_f32_16x16x32_bf16(a3, Wv[(3 * 8 + ct) * 64 + l], acc, 0, 0, 0);
        int col = ct * 16 + lo;
#pragma unroll
        for (int r = 0; r < 4; r++) {
            int grow = srow + r;
            if (grow < NN) Hd[grow * 128 + col] = f2bf(acc[r] * dv[r]);
        }
    }
}

// ---------- MFMA output GEMM: out = Xb @ Wout + bout ----------
__global__ __launch_bounds__(256) void k_gemm_out(const unsigned short* __restrict__ Xb,
                                                  const unsigned short* __restrict__ Wpk,
                                                  const float* __restrict__ b,
                                                  float* __restrict__ out) {
    int w = threadIdx.x >> 6, l = threadIdx.x & 63;
    int row0 = blockIdx.x * 64 + w * 16;
    int lo = l & 15, hi = l >> 4;
    int arow = row0 + lo; if (arow >= NN) arow = NN - 1;
    const short8* Xv = (const short8*)Xb;
    short8 a0 = Xv[arow * 16 + 0 + hi];
    short8 a1 = Xv[arow * 16 + 4 + hi];
    short8 a2 = Xv[arow * 16 + 8 + hi];
    short8 a3 = Xv[arow * 16 + 12 + hi];
    const short8* Wv = (const short8*)Wpk;
    int srow = row0 + hi * 4;
#pragma unroll
    for (int ct = 0; ct < 4; ct++) {
        f32x4 acc = {0.0f, 0.0f, 0.0f, 0.0f};
        acc = __builtin_amdgcn_mfma_f32_16x16x32_bf16(a0, Wv[(0 * 4 + ct) * 64 + l], acc, 0, 0, 0);
        acc = __builtin_amdgcn_mfma_f32_16x16x32_bf16(a1, Wv[(1 * 4 + ct) * 64 + l], acc, 0, 0, 0);
        acc = __builtin_amdgcn_mfma_f32_16x16x32_bf16(a2, Wv[(2 * 4 + ct) * 64 + l], acc, 0, 0, 0);
        acc = __builtin_amdgcn_mfma_f32_16x16x32_bf16(a3, Wv[(3 * 4 + ct) * 64 + l], acc, 0, 0, 0);
        int col = ct * 16 + lo;
        float bb = b[col];
#pragma unroll
        for (int r = 0; r < 4; r++) {
            int grow = srow + r;
            if (grow < NN) out[grow * 64 + col] = acc[r] + bb;
        }
    }
}

// ---------- CSR gather (bf16 rows): agg = dinv[d] * (Hd[d] + sum Hd[src]) ----------
__global__ __launch_bounds__(256) void k_gather(const unsigned short* __restrict__ Hd,
                                                const int* __restrict__ csr,
                                                const int* __restrict__ off,
                                                const int* __restrict__ deg,
                                                const float* __restrict__ dinv,
                                                float* __restrict__ agg) {
    int g = blockIdx.x * 16 + (threadIdx.x >> 4);
    if (g >= NN) return;
    int q = threadIdx.x & 15;
    const uint4* Hv = (const uint4*)Hd;
    int o = off[g], d = deg[g];
    uint4 h = Hv[g * 16 + q];  // self term
    float acc0 = bflo(h.x), acc1 = bfhi(h.x);
    float acc2 = bflo(h.y), acc3 = bfhi(h.y);
    float acc4 = bflo(h.z), acc5 = bfhi(h.z);
    float acc6 = bflo(h.w), acc7 = bfhi(h.w);
    for (int j = 0; j < d; j++) {
        int s = csr[o + j];
        uint4 hv = Hv[s * 16 + q];
        acc0 += bflo(hv.x); acc1 += bfhi(hv.x);
        acc2 += bflo(hv.y); acc3 += bfhi(hv.y);
        acc4 += bflo(hv.z); acc5 += bfhi(hv.z);
        acc6 += bflo(hv.w); acc7 += bfhi(hv.w);
    }
    float dvv = dinv[g];
    float4 o0, o1;
    o0.x = acc0 * dvv; o0.y = acc1 * dvv; o0.z = acc2 * dvv; o0.w = acc3 * dvv;
    o1.x = acc4 * dvv; o1.y = acc5 * dvv; o1.z = acc6 * dvv; o1.w = acc7 * dvv;
    ((float4*)agg)[g * 32 + q * 2] = o0;
    ((float4*)agg)[g * 32 + q * 2 + 1] = o1;
}

// ---------- BN column stats ----------
__global__ __launch_bounds__(256) void k_bn_stats(const float* __restrict__ agg,
                                                  float* __restrict__ sums,
                                                  float* __restrict__ sumsq) {
    int tid = threadIdx.x;
    int col = tid & 127;
    float s = 0.0f, s2 = 0.0f;
    for (int r = blockIdx.x * 2 + (tid >> 7); r < NN; r += gridDim.x * 2) {
        float v = agg[(long long)r * NH + col];
        s += v;
        s2 = fmaf(v, v, s2);
    }
    __shared__ float ls[256], ls2[256];
    ls[tid] = s; ls2[tid] = s2;
    __syncthreads();
    if (tid < 128) {
        atomicAdd(&sums[col], ls[tid] + ls[tid + 128]);
        atomicAdd(&sumsq[col], ls2[tid] + ls2[tid + 128]);
    }
}

__global__ void k_bn_fin(const float* __restrict__ sums, const float* __restrict__ sumsq,
                         const float* __restrict__ gamma, const float* __restrict__ beta,
                         float* __restrict__ scale, float* __restrict__ shift) {
    int c = threadIdx.x;
    if (c < NH) {
        float mean = sums[c] * (1.0f / NN);
        float var = sumsq[c] * (1.0f / NN) - mean * mean;
        float istd = rsqrtf(var + BN_EPS);
        float sc = istd * gamma[c];
        scale[c] = sc;
        shift[c] = beta[c] - mean * sc;
    }
}

// ---------- BN apply + ReLU + residual; writes X f32 (in-place ok) + Xb bf16 ----------
__global__ void k_elem(const float* agg, const float* __restrict__ scale,
                       const float* __restrict__ shift, const float* prev,
                       float* X, unsigned short* __restrict__ Xb) {
    int i4 = blockIdx.x * 256 + threadIdx.x;
    if (i4 >= NN * 32) return;
    int c4 = i4 & 31;
    float4 a = ((const float4*)agg)[i4];
    float4 sc = ((const float4*)scale)[c4];
    float4 sh = ((const float4*)shift)[c4];
    float4 p = ((const float4*)prev)[i4];
    float4 o;
    o.x = fmaxf(fmaf(a.x, sc.x, sh.x), 0.0f) + p.x;
    o.y = fmaxf(fmaf(a.y, sc.y, sh.y), 0.0f) + p.y;
    o.z = fmaxf(fmaf(a.z, sc.z, sh.z), 0.0f) + p.z;
    o.w = fmaxf(fmaf(a.w, sc.w, sh.w), 0.0f) + p.w;
    ((float4*)X)[i4] = o;
    uint2 u;
    u.x = (unsigned)f2bf(o.x) | ((unsigned)f2bf(o.y) << 16);
    u.y = (unsigned)f2bf(o.z) | ((unsigned)f2bf(o.w) << 16);
    ((uint2*)Xb)[i4] = u;
}

extern "C" void kernel_launch(void* const* d_in, const int* in_sizes, int n_in,
                              void* d_out, int out_size, void* d_ws, size_t ws_size,
                              hipStream_t stream) {
    const float* x    = (const float*)d_in[0];
    const int*   ei   = (const int*)d_in[1];
    const float* Ws   = (const float*)d_in[2];
    const float* gam  = (const float*)d_in[4];
    const float* bet  = (const float*)d_in[5];
    const float* Wout = (const float*)d_in[6];
    const float* bout = (const float*)d_in[7];
    float* out = (float*)d_out;

    const int* src = ei;
    const int* dst = ei + NE;

    char* p = (char*)d_ws;
    auto alloc = [&](size_t bytes) { char* r = p; p += (bytes + 255) & ~(size_t)255; return r; };
    int*   deg_i = (int*)alloc(NN * 4);
    int*   off   = (int*)alloc(NN * 4);
    int*   cur   = (int*)alloc(NN * 4);
    int*   aux   = (int*)alloc(256 * 4);
    int*   csr   = (int*)alloc((size_t)NE * 4);
    float* dinv  = (float*)alloc(NN * 4);
    float* A     = (float*)alloc((size_t)NN * NH * 4);
    float* B     = (float*)alloc((size_t)NN * NH * 4);
    unsigned short* Hd  = (unsigned short*)alloc((size_t)NN * NH * 2);
    unsigned short* Xb  = (unsigned short*)alloc((size_t)NN * NH * 2);
    unsigned short* Wpk = (unsigned short*)alloc((size_t)NL * NH * NH * 2);
    unsigned short* Wopk= (unsigned short*)alloc((size_t)NH * NO * 2);
    float* sums  = (float*)alloc(NH * 4);
    float* sumsq = (float*)alloc(NH * 4);
    float* scale = (float*)alloc(NH * 4);
    float* shift = (float*)alloc(NH * 4);

    // ---- preprocessing ----
    hipMemsetAsync(deg_i, 0, NN * 4, stream);
    hipMemsetAsync(cur, 0, NN * 4, stream);
    k_deg<<<(NE + 255) / 256, 256, 0, stream>>>(dst, deg_i);
    k_dinv<<<(NN + 255) / 256, 256, 0, stream>>>(deg_i, dinv);
    k_scan1<<<NB1, 256, 0, stream>>>(deg_i, off, aux);
    k_scan2<<<1, 256, 0, stream>>>(aux);
    k_scan3<<<NB1, 256, 0, stream>>>(off, aux);
    k_fill<<<(NE + 255) / 256, 256, 0, stream>>>(src, dst, off, cur, csr);
    k_packW<<<(NL * 16384 + 255) / 256, 256, 0, stream>>>(Ws, Wpk);
    k_packWout<<<32, 256, 0, stream>>>(Wout, Wopk);
    k_cvt<<<(NN * 32 + 255) / 256, 256, 0, stream>>>(x, Xb);

    // ---- layers ----
    const float* xcur = x;
    for (int l = 0; l < NL; l++) {
        float* AGG = (l & 1) ? B : A;
        k_gemm_mfma<<<(NN + 63) / 64, 256, 0, stream>>>(Xb, Wpk + (size_t)l * 16384, dinv, Hd);
        k_gather<<<(NN + 15) / 16, 256, 0, stream>>>(Hd, csr, off, deg_i, dinv, AGG);
        hipMemsetAsync(sums, 0, 2 * NH * sizeof(float), stream);
        k_bn_stats<<<512, 256, 0, stream>>>(AGG, sums, sumsq);
        k_bn_fin<<<1, 128, 0, stream>>>(sums, sumsq, gam + l * NH, bet + l * NH, scale, shift);
        k_elem<<<(NN * 32 + 255) / 256, 256, 0, stream>>>(AGG, scale, shift, xcur, AGG, Xb);
        xcur = AGG;
    }
    k_gemm_out<<<(NN + 63) / 64, 256, 0, stream>>>(Xb, Wopk, bout, out);
}

// Round 4
// 394.146 us; speedup vs baseline: 14.7694x; 1.2338x over previous
//
#include <hip/hip_runtime.h>

#define NN 50000
#define NE 800000
#define NH 128
#define NO 64
#define NL 4
#define BN_EPS 1e-5f
#define NB1 ((NN + 255) / 256)   // 196 scan blocks

typedef __attribute__((ext_vector_type(8))) short short8;
typedef __attribute__((ext_vector_type(4))) float f32x4;

__device__ inline unsigned short f2bf(float f) {
    unsigned int u = __float_as_uint(f);
    return (unsigned short)((u + 0x7fffu + ((u >> 16) & 1u)) >> 16);
}
__device__ inline float bflo(unsigned int u) { return __uint_as_float(u << 16); }
__device__ inline float bfhi(unsigned int u) { return __uint_as_float(u & 0xffff0000u); }
__device__ inline unsigned pk(float a, float b) {
    return (unsigned)f2bf(a) | ((unsigned)f2bf(b) << 16);
}

// ---------- degree count + per-edge rank (one atomic pass) ----------
__global__ void k_degrank(const int* __restrict__ dst, int* __restrict__ deg,
                          int* __restrict__ rank) {
    int e = blockIdx.x * 256 + threadIdx.x;
    if (e < NE) rank[e] = atomicAdd(&deg[dst[e]], 1);
}

__global__ void k_dinv(const int* __restrict__ deg, float* __restrict__ dinv) {
    int i = blockIdx.x * 256 + threadIdx.x;
    if (i < NN) dinv[i] = rsqrtf((float)deg[i] + 1.0f);  // +1 self loop
}

// ---------- 3-phase exclusive scan ----------
__global__ void k_scan1(const int* __restrict__ deg, int* __restrict__ off, int* __restrict__ aux) {
    __shared__ int ls[256];
    int i = blockIdx.x * 256 + threadIdx.x;
    int v = (i < NN) ? deg[i] : 0;
    ls[threadIdx.x] = v;
    __syncthreads();
    for (int s = 1; s < 256; s <<= 1) {
        int t = (threadIdx.x >= s) ? ls[threadIdx.x - s] : 0;
        __syncthreads();
        ls[threadIdx.x] += t;
        __syncthreads();
    }
    if (i < NN) off[i] = ls[threadIdx.x] - v;
    if (threadIdx.x == 255) aux[blockIdx.x] = ls[255];
}

__global__ void k_scan2(int* __restrict__ aux) {
    __shared__ int ls[256];
    int v = (threadIdx.x < NB1) ? aux[threadIdx.x] : 0;
    ls[threadIdx.x] = v;
    __syncthreads();
    for (int s = 1; s < 256; s <<= 1) {
        int t = (threadIdx.x >= s) ? ls[threadIdx.x - s] : 0;
        __syncthreads();
        ls[threadIdx.x] += t;
        __syncthreads();
    }
    if (threadIdx.x < NB1) aux[threadIdx.x] = ls[threadIdx.x] - v;
}

__global__ void k_scan3(int* __restrict__ off, const int* __restrict__ aux) {
    int i = blockIdx.x * 256 + threadIdx.x;
    if (i < NN) off[i] += aux[blockIdx.x];
}

// ---------- CSR fill (no atomics) ----------
__global__ void k_fill(const int* __restrict__ src, const int* __restrict__ dst,
                       const int* __restrict__ off, const int* __restrict__ rank,
                       int* __restrict__ csr) {
    int e = blockIdx.x * 256 + threadIdx.x;
    if (e < NE) csr[off[dst[e]] + rank[e]] = src[e];
}

// ---------- pack W [128][128] f32 -> MFMA B-fragment order, bf16 ----------
__global__ void k_packW(const float* __restrict__ Ws, unsigned short* __restrict__ Wpk) {
    int t = blockIdx.x * 256 + threadIdx.x;
    if (t >= NL * 16384) return;
    int l = t >> 14, r = t & 16383;
    int ks = r >> 12, ct = (r >> 9) & 7, lane = (r >> 3) & 63, i = r & 7;
    int k = ks * 32 + (lane >> 4) * 8 + i;
    int n = ct * 16 + (lane & 15);
    Wpk[t] = f2bf(Ws[l * 16384 + k * 128 + n]);
}

__global__ void k_packWout(const float* __restrict__ Wout, unsigned short* __restrict__ Wpk) {
    int r = blockIdx.x * 256 + threadIdx.x;
    if (r >= 8192) return;
    int ks = r >> 11, ct = (r >> 9) & 3, lane = (r >> 3) & 63, i = r & 7;
    int k = ks * 32 + (lane >> 4) * 8 + i;
    int n = ct * 16 + (lane & 15);
    Wpk[r] = f2bf(Wout[k * 64 + n]);
}

// ---------- layer-0 GEMM: Hd(bf16) = (x_f32 @ W0) * dinv ----------
__global__ __launch_bounds__(256) void k_fg0(const float* __restrict__ X,
                                             const unsigned short* __restrict__ Wpk,
                                             const float* __restrict__ dinv,
                                             unsigned short* __restrict__ Hd) {
    int w = threadIdx.x >> 6, l = threadIdx.x & 63;
    int row0 = blockIdx.x * 64 + w * 16;
    int lo = l & 15, hi = l >> 4;
    int arow = row0 + lo;
    int crow = (arow < NN) ? arow : NN - 1;
    short8 frag[4];
#pragma unroll
    for (int g = 0; g < 4; g++) {
        int cs = g * 32 + hi * 8;
        float4 p0 = *(const float4*)&X[(size_t)crow * NH + cs];
        float4 p1 = *(const float4*)&X[(size_t)crow * NH + cs + 4];
        short8 f;
        f[0] = (short)f2bf(p0.x); f[1] = (short)f2bf(p0.y);
        f[2] = (short)f2bf(p0.z); f[3] = (short)f2bf(p0.w);
        f[4] = (short)f2bf(p1.x); f[5] = (short)f2bf(p1.y);
        f[6] = (short)f2bf(p1.z); f[7] = (short)f2bf(p1.w);
        frag[g] = f;
    }
    const short8* Wv = (const short8*)Wpk;
    int srow = row0 + hi * 4;
    float dv[4];
#pragma unroll
    for (int r = 0; r < 4; r++) dv[r] = (srow + r < NN) ? dinv[srow + r] : 0.0f;
#pragma unroll
    for (int ct = 0; ct < 8; ct++) {
        f32x4 acc = {0.0f, 0.0f, 0.0f, 0.0f};
#pragma unroll
        for (int g = 0; g < 4; g++)
            acc = __builtin_amdgcn_mfma_f32_16x16x32_bf16(frag[g], Wv[(g * 8 + ct) * 64 + l], acc, 0, 0, 0);
        int col = ct * 16 + lo;
#pragma unroll
        for (int r = 0; r < 4; r++) {
            int grow = srow + r;
            if (grow < NN) Hd[grow * NH + col] = f2bf(acc[r] * dv[r]);
        }
    }
}

// ---------- fused: x_l = BN+ReLU+res(AGG,prev); Hd = (x_l @ W) * dinv ----------
__global__ __launch_bounds__(256) void k_fg(const unsigned short* __restrict__ AGGb,
                                            const float* __restrict__ scale,
                                            const float* __restrict__ shift,
                                            const float* __restrict__ Xprev,
                                            float* __restrict__ Xout,
                                            const unsigned short* __restrict__ Wpk,
                                            const float* __restrict__ dinv,
                                            unsigned short* __restrict__ Hd) {
    int w = threadIdx.x >> 6, l = threadIdx.x & 63;
    int row0 = blockIdx.x * 64 + w * 16;
    int lo = l & 15, hi = l >> 4;
    int arow = row0 + lo;
    bool valid = arow < NN;
    int crow = valid ? arow : NN - 1;
    short8 frag[4];
#pragma unroll
    for (int g = 0; g < 4; g++) {
        int cs = g * 32 + hi * 8;
        uint4 ab = *(const uint4*)&AGGb[(size_t)crow * NH + cs];
        float4 p0 = *(const float4*)&Xprev[(size_t)crow * NH + cs];
        float4 p1 = *(const float4*)&Xprev[(size_t)crow * NH + cs + 4];
        float4 sc0 = *(const float4*)&scale[cs];
        float4 sc1 = *(const float4*)&scale[cs + 4];
        float4 sh0 = *(const float4*)&shift[cs];
        float4 sh1 = *(const float4*)&shift[cs + 4];
        float o0 = fmaxf(fmaf(bflo(ab.x), sc0.x, sh0.x), 0.0f) + p0.x;
        float o1 = fmaxf(fmaf(bfhi(ab.x), sc0.y, sh0.y), 0.0f) + p0.y;
        float o2 = fmaxf(fmaf(bflo(ab.y), sc0.z, sh0.z), 0.0f) + p0.z;
        float o3 = fmaxf(fmaf(bfhi(ab.y), sc0.w, sh0.w), 0.0f) + p0.w;
        float o4 = fmaxf(fmaf(bflo(ab.z), sc1.x, sh1.x), 0.0f) + p1.x;
        float o5 = fmaxf(fmaf(bfhi(ab.z), sc1.y, sh1.y), 0.0f) + p1.y;
        float o6 = fmaxf(fmaf(bflo(ab.w), sc1.z, sh1.z), 0.0f) + p1.z;
        float o7 = fmaxf(fmaf(bfhi(ab.w), sc1.w, sh1.w), 0.0f) + p1.w;
        if (valid) {
            float4 s0 = {o0, o1, o2, o3}, s1 = {o4, o5, o6, o7};
            *(float4*)&Xout[(size_t)arow * NH + cs] = s0;
            *(float4*)&Xout[(size_t)arow * NH + cs + 4] = s1;
        }
        short8 f;
        f[0] = (short)f2bf(o0); f[1] = (short)f2bf(o1);
        f[2] = (short)f2bf(o2); f[3] = (short)f2bf(o3);
        f[4] = (short)f2bf(o4); f[5] = (short)f2bf(o5);
        f[6] = (short)f2bf(o6); f[7] = (short)f2bf(o7);
        frag[g] = f;
    }
    const short8* Wv = (const short8*)Wpk;
    int srow = row0 + hi * 4;
    float dv[4];
#pragma unroll
    for (int r = 0; r < 4; r++) dv[r] = (srow + r < NN) ? dinv[srow + r] : 0.0f;
#pragma unroll
    for (int ct = 0; ct < 8; ct++) {
        f32x4 acc = {0.0f, 0.0f, 0.0f, 0.0f};
#pragma unroll
        for (int g = 0; g < 4; g++)
            acc = __builtin_amdgcn_mfma_f32_16x16x32_bf16(frag[g], Wv[(g * 8 + ct) * 64 + l], acc, 0, 0, 0);
        int col = ct * 16 + lo;
#pragma unroll
        for (int r = 0; r < 4; r++) {
            int grow = srow + r;
            if (grow < NN) Hd[grow * NH + col] = f2bf(acc[r] * dv[r]);
        }
    }
}

// ---------- fused final: x_4 = BN+ReLU+res; out = x_4 @ Wout + bout ----------
__global__ __launch_bounds__(256) void k_fgout(const unsigned short* __restrict__ AGGb,
                                               const float* __restrict__ scale,
                                               const float* __restrict__ shift,
                                               const float* __restrict__ Xprev,
                                               const unsigned short* __restrict__ Wpk,
                                               const float* __restrict__ b,
                                               float* __restrict__ out) {
    int w = threadIdx.x >> 6, l = threadIdx.x & 63;
    int row0 = blockIdx.x * 64 + w * 16;
    int lo = l & 15, hi = l >> 4;
    int arow = row0 + lo;
    int crow = (arow < NN) ? arow : NN - 1;
    short8 frag[4];
#pragma unroll
    for (int g = 0; g < 4; g++) {
        int cs = g * 32 + hi * 8;
        uint4 ab = *(const uint4*)&AGGb[(size_t)crow * NH + cs];
        float4 p0 = *(const float4*)&Xprev[(size_t)crow * NH + cs];
        float4 p1 = *(const float4*)&Xprev[(size_t)crow * NH + cs + 4];
        float4 sc0 = *(const float4*)&scale[cs];
        float4 sc1 = *(const float4*)&scale[cs + 4];
        float4 sh0 = *(const float4*)&shift[cs];
        float4 sh1 = *(const float4*)&shift[cs + 4];
        short8 f;
        f[0] = (short)f2bf(fmaxf(fmaf(bflo(ab.x), sc0.x, sh0.x), 0.0f) + p0.x);
        f[1] = (short)f2bf(fmaxf(fmaf(bfhi(ab.x), sc0.y, sh0.y), 0.0f) + p0.y);
        f[2] = (short)f2bf(fmaxf(fmaf(bflo(ab.y), sc0.z, sh0.z), 0.0f) + p0.z);
        f[3] = (short)f2bf(fmaxf(fmaf(bfhi(ab.y), sc0.w, sh0.w), 0.0f) + p0.w);
        f[4] = (short)f2bf(fmaxf(fmaf(bflo(ab.z), sc1.x, sh1.x), 0.0f) + p1.x);
        f[5] = (short)f2bf(fmaxf(fmaf(bfhi(ab.z), sc1.y, sh1.y), 0.0f) + p1.y);
        f[6] = (short)f2bf(fmaxf(fmaf(bflo(ab.w), sc1.z, sh1.z), 0.0f) + p1.z);
        f[7] = (short)f2bf(fmaxf(fmaf(bfhi(ab.w), sc1.w, sh1.w), 0.0f) + p1.w);
        frag[g] = f;
    }
    const short8* Wv = (const short8*)Wpk;
    int srow = row0 + hi * 4;
#pragma unroll
    for (int ct = 0; ct < 4; ct++) {
        f32x4 acc = {0.0f, 0.0f, 0.0f, 0.0f};
#pragma unroll
        for (int g = 0; g < 4; g++)
            acc = __builtin_amdgcn_mfma_f32_16x16x32_bf16(frag[g], Wv[(g * 4 + ct) * 64 + l], acc, 0, 0, 0);
        int col = ct * 16 + lo;
        float bb = b[col];
#pragma unroll
        for (int r = 0; r < 4; r++) {
            int grow = srow + r;
            if (grow < NN) out[grow * NO + col] = acc[r] + bb;
        }
    }
}

// ---------- CSR gather: AGGb(bf16) = dinv[d]*(Hd[d] + sum Hd[src]) ----------
__global__ __launch_bounds__(256) void k_gather(const unsigned short* __restrict__ Hd,
                                                const int* __restrict__ csr,
                                                const int* __restrict__ off,
                                                const int* __restrict__ deg,
                                                const float* __restrict__ dinv,
                                                unsigned short* __restrict__ AGGb) {
    int g = blockIdx.x * 16 + (threadIdx.x >> 4);
    if (g >= NN) return;
    int q = threadIdx.x & 15;
    const uint4* Hv = (const uint4*)Hd;
    int o = off[g], d = deg[g];
    uint4 h = Hv[g * 16 + q];  // self term
    float a0 = bflo(h.x), a1 = bfhi(h.x);
    float a2 = bflo(h.y), a3 = bfhi(h.y);
    float a4 = bflo(h.z), a5 = bfhi(h.z);
    float a6 = bflo(h.w), a7 = bfhi(h.w);
    int j = 0;
    for (; j + 2 <= d; j += 2) {
        int s0 = csr[o + j], s1 = csr[o + j + 1];
        uint4 h0 = Hv[s0 * 16 + q];
        uint4 h1 = Hv[s1 * 16 + q];
        a0 += bflo(h0.x) + bflo(h1.x); a1 += bfhi(h0.x) + bfhi(h1.x);
        a2 += bflo(h0.y) + bflo(h1.y); a3 += bfhi(h0.y) + bfhi(h1.y);
        a4 += bflo(h0.z) + bflo(h1.z); a5 += bfhi(h0.z) + bfhi(h1.z);
        a6 += bflo(h0.w) + bflo(h1.w); a7 += bfhi(h0.w) + bfhi(h1.w);
    }
    if (j < d) {
        int s0 = csr[o + j];
        uint4 h0 = Hv[s0 * 16 + q];
        a0 += bflo(h0.x); a1 += bfhi(h0.x);
        a2 += bflo(h0.y); a3 += bfhi(h0.y);
        a4 += bflo(h0.z); a5 += bfhi(h0.z);
        a6 += bflo(h0.w); a7 += bfhi(h0.w);
    }
    float dv = dinv[g];
    uint4 u;
    u.x = pk(a0 * dv, a1 * dv);
    u.y = pk(a2 * dv, a3 * dv);
    u.z = pk(a4 * dv, a5 * dv);
    u.w = pk(a6 * dv, a7 * dv);
    ((uint4*)AGGb)[g * 16 + q] = u;
}

// ---------- BN column stats (bf16 input) ----------
__global__ __launch_bounds__(256) void k_bn_stats(const unsigned short* __restrict__ AGGb,
                                                  float* __restrict__ sums,
                                                  float* __restrict__ sumsq) {
    int tid = threadIdx.x;
    int col = tid & 127;
    float s = 0.0f, s2 = 0.0f;
    for (int r = blockIdx.x * 2 + (tid >> 7); r < NN; r += gridDim.x * 2) {
        float v = bflo((unsigned)AGGb[(size_t)r * NH + col]);
        s += v;
        s2 = fmaf(v, v, s2);
    }
    __shared__ float ls[256], ls2[256];
    ls[tid] = s; ls2[tid] = s2;
    __syncthreads();
    if (tid < 128) {
        atomicAdd(&sums[col], ls[tid] + ls[tid + 128]);
        atomicAdd(&sumsq[col], ls2[tid] + ls2[tid + 128]);
    }
}

__global__ void k_bn_fin(const float* __restrict__ sums, const float* __restrict__ sumsq,
                         const float* __restrict__ gamma, const float* __restrict__ beta,
                         float* __restrict__ scale, float* __restrict__ shift) {
    int c = threadIdx.x;
    if (c < NH) {
        float mean = sums[c] * (1.0f / NN);
        float var = sumsq[c] * (1.0f / NN) - mean * mean;
        float istd = rsqrtf(var + BN_EPS);
        float sc = istd * gamma[c];
        scale[c] = sc;
        shift[c] = beta[c] - mean * sc;
    }
}

extern "C" void kernel_launch(void* const* d_in, const int* in_sizes, int n_in,
                              void* d_out, int out_size, void* d_ws, size_t ws_size,
                              hipStream_t stream) {
    const float* x    = (const float*)d_in[0];
    const int*   ei   = (const int*)d_in[1];
    const float* Ws   = (const float*)d_in[2];
    const float* gam  = (const float*)d_in[4];
    const float* bet  = (const float*)d_in[5];
    const float* Wout = (const float*)d_in[6];
    const float* bout = (const float*)d_in[7];
    float* out = (float*)d_out;

    const int* src = ei;
    const int* dst = ei + NE;

    char* p = (char*)d_ws;
    auto alloc = [&](size_t bytes) { char* r = p; p += (bytes + 255) & ~(size_t)255; return r; };
    int*   deg_i = (int*)alloc(NN * 4);
    int*   off   = (int*)alloc(NN * 4);
    int*   rank  = (int*)alloc((size_t)NE * 4);
    int*   aux   = (int*)alloc(256 * 4);
    int*   csr   = (int*)alloc((size_t)NE * 4);
    float* dinv  = (float*)alloc(NN * 4);
    float* XA    = (float*)alloc((size_t)NN * NH * 4);
    float* XB    = (float*)alloc((size_t)NN * NH * 4);
    unsigned short* Hd   = (unsigned short*)alloc((size_t)NN * NH * 2);
    unsigned short* AGGb = (unsigned short*)alloc((size_t)NN * NH * 2);
    unsigned short* Wpk  = (unsigned short*)alloc((size_t)NL * NH * NH * 2);
    unsigned short* Wopk = (unsigned short*)alloc((size_t)NH * NO * 2);
    float* sums  = (float*)alloc(NH * 4);
    float* sumsq = (float*)alloc(NH * 4);
    float* scale = (float*)alloc(NH * 4);
    float* shift = (float*)alloc(NH * 4);

    // ---- preprocessing ----
    hipMemsetAsync(deg_i, 0, NN * 4, stream);
    k_degrank<<<(NE + 255) / 256, 256, 0, stream>>>(dst, deg_i, rank);
    k_dinv<<<(NN + 255) / 256, 256, 0, stream>>>(deg_i, dinv);
    k_scan1<<<NB1, 256, 0, stream>>>(deg_i, off, aux);
    k_scan2<<<1, 256, 0, stream>>>(aux);
    k_scan3<<<NB1, 256, 0, stream>>>(off, aux);
    k_fill<<<(NE + 255) / 256, 256, 0, stream>>>(src, dst, off, rank, csr);
    k_packW<<<(NL * 16384 + 255) / 256, 256, 0, stream>>>(Ws, Wpk);
    k_packWout<<<32, 256, 0, stream>>>(Wout, Wopk);

    const int GB = (NN + 63) / 64;  // fused gemm grid

    // ---- layer 0 GEMM from f32 input ----
    k_fg0<<<GB, 256, 0, stream>>>(x, Wpk, dinv, Hd);

    const float* xprev = x;
    for (int l = 0; l < NL; l++) {
        k_gather<<<(NN + 15) / 16, 256, 0, stream>>>(Hd, csr, off, deg_i, dinv, AGGb);
        hipMemsetAsync(sums, 0, 2 * NH * sizeof(float), stream);
        k_bn_stats<<<512, 256, 0, stream>>>(AGGb, sums, sumsq);
        k_bn_fin<<<1, 128, 0, stream>>>(sums, sumsq, gam + l * NH, bet + l * NH, scale, shift);
        if (l < NL - 1) {
            float* Xout = (l & 1) ? XB : XA;
            k_fg<<<GB, 256, 0, stream>>>(AGGb, scale, shift, xprev, Xout,
                                         Wpk + (size_t)(l + 1) * 16384, dinv, Hd);
            xprev = Xout;
        } else {
            k_fgout<<<GB, 256, 0, stream>>>(AGGb, scale, shift, xprev, Wopk, bout, out);
        }
    }
}

// Round 5
// 385.762 us; speedup vs baseline: 15.0904x; 1.0217x over previous
//
#include <hip/hip_runtime.h>

#define NN 50000
#define NE 800000
#define NH 128
#define NO 64
#define NL 4
#define BN_EPS 1e-5f
#define NB1 ((NN + 255) / 256)   // 196 scan blocks

typedef __attribute__((ext_vector_type(8))) short short8;
typedef __attribute__((ext_vector_type(4))) float f32x4;

__device__ inline unsigned short f2bf(float f) {
    unsigned int u = __float_as_uint(f);
    return (unsigned short)((u + 0x7fffu + ((u >> 16) & 1u)) >> 16);
}
__device__ inline float bflo(unsigned int u) { return __uint_as_float(u << 16); }
__device__ inline float bfhi(unsigned int u) { return __uint_as_float(u & 0xffff0000u); }
__device__ inline unsigned pk(float a, float b) {
    return (unsigned)f2bf(a) | ((unsigned)f2bf(b) << 16);
}

// ---------- degree count + per-edge rank, 4 edges/thread ----------
__global__ void k_degrank(const int* __restrict__ dst, int* __restrict__ deg,
                          int* __restrict__ rank) {
    int base = (blockIdx.x * 256 + threadIdx.x) * 4;
    if (base >= NE) return;
    int4 d4 = *(const int4*)&dst[base];
    int4 r4;
    r4.x = atomicAdd(&deg[d4.x], 1);
    r4.y = atomicAdd(&deg[d4.y], 1);
    r4.z = atomicAdd(&deg[d4.z], 1);
    r4.w = atomicAdd(&deg[d4.w], 1);
    *(int4*)&rank[base] = r4;
}

// ---------- scan phase 1 + dinv fused ----------
__global__ void k_scan1(const int* __restrict__ deg, int* __restrict__ off,
                        int* __restrict__ aux, float* __restrict__ dinv) {
    __shared__ int ls[256];
    int i = blockIdx.x * 256 + threadIdx.x;
    int v = (i < NN) ? deg[i] : 0;
    ls[threadIdx.x] = v;
    __syncthreads();
    for (int s = 1; s < 256; s <<= 1) {
        int t = (threadIdx.x >= s) ? ls[threadIdx.x - s] : 0;
        __syncthreads();
        ls[threadIdx.x] += t;
        __syncthreads();
    }
    if (i < NN) {
        off[i] = ls[threadIdx.x] - v;
        dinv[i] = rsqrtf((float)v + 1.0f);  // +1 self loop
    }
    if (threadIdx.x == 255) aux[blockIdx.x] = ls[255];
}

__global__ void k_scan2(int* __restrict__ aux) {
    __shared__ int ls[256];
    int v = (threadIdx.x < NB1) ? aux[threadIdx.x] : 0;
    ls[threadIdx.x] = v;
    __syncthreads();
    for (int s = 1; s < 256; s <<= 1) {
        int t = (threadIdx.x >= s) ? ls[threadIdx.x - s] : 0;
        __syncthreads();
        ls[threadIdx.x] += t;
        __syncthreads();
    }
    if (threadIdx.x < NB1) aux[threadIdx.x] = ls[threadIdx.x] - v;
}

__global__ void k_scan3(int* __restrict__ off, const int* __restrict__ aux) {
    int i = blockIdx.x * 256 + threadIdx.x;
    if (i < NN) off[i] += aux[blockIdx.x];
}

// ---------- CSR fill (no atomics), 4 edges/thread ----------
__global__ void k_fill(const int* __restrict__ src, const int* __restrict__ dst,
                       const int* __restrict__ off, const int* __restrict__ rank,
                       int* __restrict__ csr) {
    int base = (blockIdx.x * 256 + threadIdx.x) * 4;
    if (base >= NE) return;
    int4 d4 = *(const int4*)&dst[base];
    int4 r4 = *(const int4*)&rank[base];
    int4 s4 = *(const int4*)&src[base];
    int o0 = off[d4.x], o1 = off[d4.y], o2 = off[d4.z], o3 = off[d4.w];
    csr[o0 + r4.x] = s4.x;
    csr[o1 + r4.y] = s4.y;
    csr[o2 + r4.z] = s4.z;
    csr[o3 + r4.w] = s4.w;
}

// ---------- pack W + Wout -> MFMA B-fragment order, bf16 ----------
__global__ void k_pack(const float* __restrict__ Ws, const float* __restrict__ Wout,
                       unsigned short* __restrict__ Wpk, unsigned short* __restrict__ Wopk) {
    int t = blockIdx.x * 256 + threadIdx.x;
    if (t < NL * 16384) {
        int l = t >> 14, r = t & 16383;
        int ks = r >> 12, ct = (r >> 9) & 7, lane = (r >> 3) & 63, i = r & 7;
        int k = ks * 32 + (lane >> 4) * 8 + i;
        int n = ct * 16 + (lane & 15);
        Wpk[t] = f2bf(Ws[l * 16384 + k * 128 + n]);
    } else if (t < NL * 16384 + 8192) {
        int r = t - NL * 16384;
        int ks = r >> 11, ct = (r >> 9) & 3, lane = (r >> 3) & 63, i = r & 7;
        int k = ks * 32 + (lane >> 4) * 8 + i;
        int n = ct * 16 + (lane & 15);
        Wopk[r] = f2bf(Wout[k * 64 + n]);
    }
}

// ---------- layer-0 GEMM: Hd(bf16) = (x_f32 @ W0) * dinv ----------
__global__ __launch_bounds__(256) void k_fg0(const float* __restrict__ X,
                                             const unsigned short* __restrict__ Wpk,
                                             const float* __restrict__ dinv,
                                             unsigned short* __restrict__ Hd) {
    int w = threadIdx.x >> 6, l = threadIdx.x & 63;
    int row0 = blockIdx.x * 64 + w * 16;
    int lo = l & 15, hi = l >> 4;
    int arow = row0 + lo;
    int crow = (arow < NN) ? arow : NN - 1;
    short8 frag[4];
#pragma unroll
    for (int g = 0; g < 4; g++) {
        int cs = g * 32 + hi * 8;
        float4 p0 = *(const float4*)&X[(size_t)crow * NH + cs];
        float4 p1 = *(const float4*)&X[(size_t)crow * NH + cs + 4];
        short8 f;
        f[0] = (short)f2bf(p0.x); f[1] = (short)f2bf(p0.y);
        f[2] = (short)f2bf(p0.z); f[3] = (short)f2bf(p0.w);
        f[4] = (short)f2bf(p1.x); f[5] = (short)f2bf(p1.y);
        f[6] = (short)f2bf(p1.z); f[7] = (short)f2bf(p1.w);
        frag[g] = f;
    }
    const short8* Wv = (const short8*)Wpk;
    int srow = row0 + hi * 4;
    float dv[4];
#pragma unroll
    for (int r = 0; r < 4; r++) dv[r] = (srow + r < NN) ? dinv[srow + r] : 0.0f;
#pragma unroll
    for (int ct = 0; ct < 8; ct++) {
        f32x4 acc = {0.0f, 0.0f, 0.0f, 0.0f};
#pragma unroll
        for (int g = 0; g < 4; g++)
            acc = __builtin_amdgcn_mfma_f32_16x16x32_bf16(frag[g], Wv[(g * 8 + ct) * 64 + l], acc, 0, 0, 0);
        int col = ct * 16 + lo;
#pragma unroll
        for (int r = 0; r < 4; r++) {
            int grow = srow + r;
            if (grow < NN) Hd[grow * NH + col] = f2bf(acc[r] * dv[r]);
        }
    }
}

// ---------- fused: x_l = BN+ReLU+res(AGG,prev); Hd = (x_l @ W) * dinv ----------
__global__ __launch_bounds__(256) void k_fg(const unsigned short* __restrict__ AGGb,
                                            const float* __restrict__ scale,
                                            const float* __restrict__ shift,
                                            const float* __restrict__ Xprev,
                                            float* __restrict__ Xout,
                                            const unsigned short* __restrict__ Wpk,
                                            const float* __restrict__ dinv,
                                            unsigned short* __restrict__ Hd) {
    int w = threadIdx.x >> 6, l = threadIdx.x & 63;
    int row0 = blockIdx.x * 64 + w * 16;
    int lo = l & 15, hi = l >> 4;
    int arow = row0 + lo;
    bool valid = arow < NN;
    int crow = valid ? arow : NN - 1;
    short8 frag[4];
#pragma unroll
    for (int g = 0; g < 4; g++) {
        int cs = g * 32 + hi * 8;
        uint4 ab = *(const uint4*)&AGGb[(size_t)crow * NH + cs];
        float4 p0 = *(const float4*)&Xprev[(size_t)crow * NH + cs];
        float4 p1 = *(const float4*)&Xprev[(size_t)crow * NH + cs + 4];
        float4 sc0 = *(const float4*)&scale[cs];
        float4 sc1 = *(const float4*)&scale[cs + 4];
        float4 sh0 = *(const float4*)&shift[cs];
        float4 sh1 = *(const float4*)&shift[cs + 4];
        float o0 = fmaxf(fmaf(bflo(ab.x), sc0.x, sh0.x), 0.0f) + p0.x;
        float o1 = fmaxf(fmaf(bfhi(ab.x), sc0.y, sh0.y), 0.0f) + p0.y;
        float o2 = fmaxf(fmaf(bflo(ab.y), sc0.z, sh0.z), 0.0f) + p0.z;
        float o3 = fmaxf(fmaf(bfhi(ab.y), sc0.w, sh0.w), 0.0f) + p0.w;
        float o4 = fmaxf(fmaf(bflo(ab.z), sc1.x, sh1.x), 0.0f) + p1.x;
        float o5 = fmaxf(fmaf(bfhi(ab.z), sc1.y, sh1.y), 0.0f) + p1.y;
        float o6 = fmaxf(fmaf(bflo(ab.w), sc1.z, sh1.z), 0.0f) + p1.z;
        float o7 = fmaxf(fmaf(bfhi(ab.w), sc1.w, sh1.w), 0.0f) + p1.w;
        if (valid) {
            float4 s0 = {o0, o1, o2, o3}, s1 = {o4, o5, o6, o7};
            *(float4*)&Xout[(size_t)arow * NH + cs] = s0;
            *(float4*)&Xout[(size_t)arow * NH + cs + 4] = s1;
        }
        short8 f;
        f[0] = (short)f2bf(o0); f[1] = (short)f2bf(o1);
        f[2] = (short)f2bf(o2); f[3] = (short)f2bf(o3);
        f[4] = (short)f2bf(o4); f[5] = (short)f2bf(o5);
        f[6] = (short)f2bf(o6); f[7] = (short)f2bf(o7);
        frag[g] = f;
    }
    const short8* Wv = (const short8*)Wpk;
    int srow = row0 + hi * 4;
    float dv[4];
#pragma unroll
    for (int r = 0; r < 4; r++) dv[r] = (srow + r < NN) ? dinv[srow + r] : 0.0f;
#pragma unroll
    for (int ct = 0; ct < 8; ct++) {
        f32x4 acc = {0.0f, 0.0f, 0.0f, 0.0f};
#pragma unroll
        for (int g = 0; g < 4; g++)
            acc = __builtin_amdgcn_mfma_f32_16x16x32_bf16(frag[g], Wv[(g * 8 + ct) * 64 + l], acc, 0, 0, 0);
        int col = ct * 16 + lo;
#pragma unroll
        for (int r = 0; r < 4; r++) {
            int grow = srow + r;
            if (grow < NN) Hd[grow * NH + col] = f2bf(acc[r] * dv[r]);
        }
    }
}

// ---------- fused final: x_4 = BN+ReLU+res; out = x_4 @ Wout + bout ----------
__global__ __launch_bounds__(256) void k_fgout(const unsigned short* __restrict__ AGGb,
                                               const float* __restrict__ scale,
                                               const float* __restrict__ shift,
                                               const float* __restrict__ Xprev,
                                               const unsigned short* __restrict__ Wpk,
                                               const float* __restrict__ b,
                                               float* __restrict__ out) {
    int w = threadIdx.x >> 6, l = threadIdx.x & 63;
    int row0 = blockIdx.x * 64 + w * 16;
    int lo = l & 15, hi = l >> 4;
    int arow = row0 + lo;
    int crow = (arow < NN) ? arow : NN - 1;
    short8 frag[4];
#pragma unroll
    for (int g = 0; g < 4; g++) {
        int cs = g * 32 + hi * 8;
        uint4 ab = *(const uint4*)&AGGb[(size_t)crow * NH + cs];
        float4 p0 = *(const float4*)&Xprev[(size_t)crow * NH + cs];
        float4 p1 = *(const float4*)&Xprev[(size_t)crow * NH + cs + 4];
        float4 sc0 = *(const float4*)&scale[cs];
        float4 sc1 = *(const float4*)&scale[cs + 4];
        float4 sh0 = *(const float4*)&shift[cs];
        float4 sh1 = *(const float4*)&shift[cs + 4];
        short8 f;
        f[0] = (short)f2bf(fmaxf(fmaf(bflo(ab.x), sc0.x, sh0.x), 0.0f) + p0.x);
        f[1] = (short)f2bf(fmaxf(fmaf(bfhi(ab.x), sc0.y, sh0.y), 0.0f) + p0.y);
        f[2] = (short)f2bf(fmaxf(fmaf(bflo(ab.y), sc0.z, sh0.z), 0.0f) + p0.z);
        f[3] = (short)f2bf(fmaxf(fmaf(bfhi(ab.y), sc0.w, sh0.w), 0.0f) + p0.w);
        f[4] = (short)f2bf(fmaxf(fmaf(bflo(ab.z), sc1.x, sh1.x), 0.0f) + p1.x);
        f[5] = (short)f2bf(fmaxf(fmaf(bfhi(ab.z), sc1.y, sh1.y), 0.0f) + p1.y);
        f[6] = (short)f2bf(fmaxf(fmaf(bflo(ab.w), sc1.z, sh1.z), 0.0f) + p1.z);
        f[7] = (short)f2bf(fmaxf(fmaf(bfhi(ab.w), sc1.w, sh1.w), 0.0f) + p1.w);
        frag[g] = f;
    }
    const short8* Wv = (const short8*)Wpk;
    int srow = row0 + hi * 4;
#pragma unroll
    for (int ct = 0; ct < 4; ct++) {
        f32x4 acc = {0.0f, 0.0f, 0.0f, 0.0f};
#pragma unroll
        for (int g = 0; g < 4; g++)
            acc = __builtin_amdgcn_mfma_f32_16x16x32_bf16(frag[g], Wv[(g * 4 + ct) * 64 + l], acc, 0, 0, 0);
        int col = ct * 16 + lo;
        float bb = b[col];
#pragma unroll
        for (int r = 0; r < 4; r++) {
            int grow = srow + r;
            if (grow < NN) out[grow * NO + col] = acc[r] + bb;
        }
    }
}

// ---------- CSR gather: AGGb(bf16) = dinv[d]*(Hd[d] + sum Hd[src]), 4-deep ----------
__global__ __launch_bounds__(256) void k_gather(const unsigned short* __restrict__ Hd,
                                                const int* __restrict__ csr,
                                                const int* __restrict__ off,
                                                const int* __restrict__ deg,
                                                const float* __restrict__ dinv,
                                                unsigned short* __restrict__ AGGb) {
    int g = blockIdx.x * 16 + (threadIdx.x >> 4);
    if (g >= NN) return;
    int q = threadIdx.x & 15;
    const uint4* Hv = (const uint4*)Hd;
    int o = off[g], d = deg[g];
    uint4 h = Hv[g * 16 + q];  // self term
    float a0 = bflo(h.x), a1 = bfhi(h.x);
    float a2 = bflo(h.y), a3 = bfhi(h.y);
    float a4 = bflo(h.z), a5 = bfhi(h.z);
    float a6 = bflo(h.w), a7 = bfhi(h.w);
    int j = 0;
    for (; j + 4 <= d; j += 4) {
        int s0 = csr[o + j], s1 = csr[o + j + 1];
        int s2 = csr[o + j + 2], s3 = csr[o + j + 3];
        uint4 h0 = Hv[s0 * 16 + q];
        uint4 h1 = Hv[s1 * 16 + q];
        uint4 h2 = Hv[s2 * 16 + q];
        uint4 h3 = Hv[s3 * 16 + q];
        a0 += (bflo(h0.x) + bflo(h1.x)) + (bflo(h2.x) + bflo(h3.x));
        a1 += (bfhi(h0.x) + bfhi(h1.x)) + (bfhi(h2.x) + bfhi(h3.x));
        a2 += (bflo(h0.y) + bflo(h1.y)) + (bflo(h2.y) + bflo(h3.y));
        a3 += (bfhi(h0.y) + bfhi(h1.y)) + (bfhi(h2.y) + bfhi(h3.y));
        a4 += (bflo(h0.z) + bflo(h1.z)) + (bflo(h2.z) + bflo(h3.z));
        a5 += (bfhi(h0.z) + bfhi(h1.z)) + (bfhi(h2.z) + bfhi(h3.z));
        a6 += (bflo(h0.w) + bflo(h1.w)) + (bflo(h2.w) + bflo(h3.w));
        a7 += (bfhi(h0.w) + bfhi(h1.w)) + (bfhi(h2.w) + bfhi(h3.w));
    }
    for (; j < d; j++) {
        int s0 = csr[o + j];
        uint4 h0 = Hv[s0 * 16 + q];
        a0 += bflo(h0.x); a1 += bfhi(h0.x);
        a2 += bflo(h0.y); a3 += bfhi(h0.y);
        a4 += bflo(h0.z); a5 += bfhi(h0.z);
        a6 += bflo(h0.w); a7 += bfhi(h0.w);
    }
    float dv = dinv[g];
    uint4 u;
    u.x = pk(a0 * dv, a1 * dv);
    u.y = pk(a2 * dv, a3 * dv);
    u.z = pk(a4 * dv, a5 * dv);
    u.w = pk(a6 * dv, a7 * dv);
    ((uint4*)AGGb)[g * 16 + q] = u;
}

// ---------- BN column stats (bf16, vectorized uint2) ----------
__global__ __launch_bounds__(256) void k_bn_stats(const unsigned short* __restrict__ AGGb,
                                                  float* __restrict__ sums,
                                                  float* __restrict__ sumsq) {
    int tid = threadIdx.x;
    int cq = tid & 31;   // 4 columns: cq*4..cq*4+3
    int rg = tid >> 5;   // 8 row groups
    float s0 = 0, s1 = 0, s2 = 0, s3 = 0;
    float q0 = 0, q1 = 0, q2 = 0, q3 = 0;
    for (int r = blockIdx.x * 8 + rg; r < NN; r += gridDim.x * 8) {
        uint2 u = *(const uint2*)&AGGb[(size_t)r * NH + cq * 4];
        float v0 = bflo(u.x), v1 = bfhi(u.x), v2 = bflo(u.y), v3 = bfhi(u.y);
        s0 += v0; s1 += v1; s2 += v2; s3 += v3;
        q0 = fmaf(v0, v0, q0); q1 = fmaf(v1, v1, q1);
        q2 = fmaf(v2, v2, q2); q3 = fmaf(v3, v3, q3);
    }
    __shared__ float ls[256][4], lq[256][4];
    ls[tid][0] = s0; ls[tid][1] = s1; ls[tid][2] = s2; ls[tid][3] = s3;
    lq[tid][0] = q0; lq[tid][1] = q1; lq[tid][2] = q2; lq[tid][3] = q3;
    __syncthreads();
    if (rg == 0) {
        float t0 = s0, t1 = s1, t2 = s2, t3 = s3;
        float u0 = q0, u1 = q1, u2 = q2, u3 = q3;
        for (int g = 1; g < 8; g++) {
            t0 += ls[g * 32 + cq][0]; t1 += ls[g * 32 + cq][1];
            t2 += ls[g * 32 + cq][2]; t3 += ls[g * 32 + cq][3];
            u0 += lq[g * 32 + cq][0]; u1 += lq[g * 32 + cq][1];
            u2 += lq[g * 32 + cq][2]; u3 += lq[g * 32 + cq][3];
        }
        atomicAdd(&sums[cq * 4 + 0], t0); atomicAdd(&sums[cq * 4 + 1], t1);
        atomicAdd(&sums[cq * 4 + 2], t2); atomicAdd(&sums[cq * 4 + 3], t3);
        atomicAdd(&sumsq[cq * 4 + 0], u0); atomicAdd(&sumsq[cq * 4 + 1], u1);
        atomicAdd(&sumsq[cq * 4 + 2], u2); atomicAdd(&sumsq[cq * 4 + 3], u3);
    }
}

__global__ void k_bn_fin(const float* __restrict__ sums, const float* __restrict__ sumsq,
                         const float* __restrict__ gamma, const float* __restrict__ beta,
                         float* __restrict__ scale, float* __restrict__ shift) {
    int c = threadIdx.x;
    if (c < NH) {
        float mean = sums[c] * (1.0f / NN);
        float var = sumsq[c] * (1.0f / NN) - mean * mean;
        float istd = rsqrtf(var + BN_EPS);
        float sc = istd * gamma[c];
        scale[c] = sc;
        shift[c] = beta[c] - mean * sc;
    }
}

extern "C" void kernel_launch(void* const* d_in, const int* in_sizes, int n_in,
                              void* d_out, int out_size, void* d_ws, size_t ws_size,
                              hipStream_t stream) {
    const float* x    = (const float*)d_in[0];
    const int*   ei   = (const int*)d_in[1];
    const float* Ws   = (const float*)d_in[2];
    const float* gam  = (const float*)d_in[4];
    const float* bet  = (const float*)d_in[5];
    const float* Wout = (const float*)d_in[6];
    const float* bout = (const float*)d_in[7];
    float* out = (float*)d_out;

    const int* src = ei;
    const int* dst = ei + NE;

    char* p = (char*)d_ws;
    auto alloc = [&](size_t bytes) { char* r = p; p += (bytes + 255) & ~(size_t)255; return r; };
    int*   deg_i = (int*)alloc(NN * 4);
    int*   off   = (int*)alloc(NN * 4);
    int*   rank  = (int*)alloc((size_t)NE * 4);
    int*   aux   = (int*)alloc(256 * 4);
    int*   csr   = (int*)alloc((size_t)NE * 4);
    float* dinv  = (float*)alloc(NN * 4);
    float* XA    = (float*)alloc((size_t)NN * NH * 4);
    float* XB    = (float*)alloc((size_t)NN * NH * 4);
    unsigned short* Hd   = (unsigned short*)alloc((size_t)NN * NH * 2);
    unsigned short* AGGb = (unsigned short*)alloc((size_t)NN * NH * 2);
    unsigned short* Wpk  = (unsigned short*)alloc((size_t)NL * NH * NH * 2);
    unsigned short* Wopk = (unsigned short*)alloc((size_t)NH * NO * 2);
    float* stats = (float*)alloc(NL * 2 * NH * 4);   // [layer][sums|sumsq]
    float* scale = (float*)alloc(NH * 4);
    float* shift = (float*)alloc(NH * 4);

    // ---- preprocessing ----
    hipMemsetAsync(deg_i, 0, NN * 4, stream);
    hipMemsetAsync(stats, 0, NL * 2 * NH * 4, stream);
    k_degrank<<<(NE / 4 + 255) / 256, 256, 0, stream>>>(dst, deg_i, rank);
    k_scan1<<<NB1, 256, 0, stream>>>(deg_i, off, aux, dinv);
    k_scan2<<<1, 256, 0, stream>>>(aux);
    k_scan3<<<NB1, 256, 0, stream>>>(off, aux);
    k_fill<<<(NE / 4 + 255) / 256, 256, 0, stream>>>(src, dst, off, rank, csr);
    k_pack<<<(NL * 16384 + 8192 + 255) / 256, 256, 0, stream>>>(Ws, Wout, Wpk, Wopk);

    const int GB = (NN + 63) / 64;

    // ---- layer 0 GEMM from f32 input ----
    k_fg0<<<GB, 256, 0, stream>>>(x, Wpk, dinv, Hd);

    const float* xprev = x;
    for (int l = 0; l < NL; l++) {
        float* sums  = stats + (size_t)l * 2 * NH;
        float* sumsq = sums + NH;
        k_gather<<<(NN + 15) / 16, 256, 0, stream>>>(Hd, csr, off, deg_i, dinv, AGGb);
        k_bn_stats<<<128, 256, 0, stream>>>(AGGb, sums, sumsq);
        k_bn_fin<<<1, 128, 0, stream>>>(sums, sumsq, gam + l * NH, bet + l * NH, scale, shift);
        if (l < NL - 1) {
            float* Xout = (l & 1) ? XB : XA;
            k_fg<<<GB, 256, 0, stream>>>(AGGb, scale, shift, xprev, Xout,
                                         Wpk + (size_t)(l + 1) * 16384, dinv, Hd);
            xprev = Xout;
        } else {
            k_fgout<<<GB, 256, 0, stream>>>(AGGb, scale, shift, xprev, Wopk, bout, out);
        }
    }
}

// Round 6
// 320.396 us; speedup vs baseline: 18.1691x; 1.2040x over previous
//
#include <hip/hip_runtime.h>

#define NN 50000
#define NE 800000
#define NH 128
#define NO 64
#define NL 4
#define BN_EPS 1e-5f
#define NB1 ((NN + 255) / 256)   // 196 scan blocks
#define NGB (NN / 16)            // 3125 gather blocks

typedef __attribute__((ext_vector_type(8))) short short8;
typedef __attribute__((ext_vector_type(4))) float f32x4;

__device__ inline unsigned short f2bf(float f) {
    unsigned int u = __float_as_uint(f);
    return (unsigned short)((u + 0x7fffu + ((u >> 16) & 1u)) >> 16);
}
__device__ inline float bflo(unsigned int u) { return __uint_as_float(u << 16); }
__device__ inline float bfhi(unsigned int u) { return __uint_as_float(u & 0xffff0000u); }
__device__ inline unsigned pk(float a, float b) {
    return (unsigned)f2bf(a) | ((unsigned)f2bf(b) << 16);
}

// ---------- degree count + per-edge rank, 2 edges/thread ----------
__global__ void k_degrank(const int* __restrict__ dst, int* __restrict__ deg,
                          int* __restrict__ rank) {
    int base = (blockIdx.x * 256 + threadIdx.x) * 2;
    if (base >= NE) return;
    int2 d2 = *(const int2*)&dst[base];
    int2 r2;
    r2.x = atomicAdd(&deg[d2.x], 1);
    r2.y = atomicAdd(&deg[d2.y], 1);
    *(int2*)&rank[base] = r2;
}

// ---------- scan phase 1 + dinv fused ----------
__global__ void k_scan1(const int* __restrict__ deg, int* __restrict__ off,
                        int* __restrict__ aux, float* __restrict__ dinv) {
    __shared__ int ls[256];
    int i = blockIdx.x * 256 + threadIdx.x;
    int v = (i < NN) ? deg[i] : 0;
    ls[threadIdx.x] = v;
    __syncthreads();
    for (int s = 1; s < 256; s <<= 1) {
        int t = (threadIdx.x >= s) ? ls[threadIdx.x - s] : 0;
        __syncthreads();
        ls[threadIdx.x] += t;
        __syncthreads();
    }
    if (i < NN) {
        off[i] = ls[threadIdx.x] - v;     // block-local exclusive
        dinv[i] = rsqrtf((float)v + 1.0f);  // +1 self loop
    }
    if (threadIdx.x == 255) aux[blockIdx.x] = ls[255];
}

__global__ void k_scan2(int* __restrict__ aux) {
    __shared__ int ls[256];
    int v = (threadIdx.x < NB1) ? aux[threadIdx.x] : 0;
    ls[threadIdx.x] = v;
    __syncthreads();
    for (int s = 1; s < 256; s <<= 1) {
        int t = (threadIdx.x >= s) ? ls[threadIdx.x - s] : 0;
        __syncthreads();
        ls[threadIdx.x] += t;
        __syncthreads();
    }
    if (threadIdx.x < NB1) aux[threadIdx.x] = ls[threadIdx.x] - v;  // exclusive block offsets
}

// ---------- CSR fill (no atomics, aux folded), 4 edges/thread ----------
__global__ void k_fill(const int* __restrict__ src, const int* __restrict__ dst,
                       const int* __restrict__ off, const int* __restrict__ aux,
                       const int* __restrict__ rank, int* __restrict__ csr) {
    int base = (blockIdx.x * 256 + threadIdx.x) * 4;
    if (base >= NE) return;
    int4 d4 = *(const int4*)&dst[base];
    int4 r4 = *(const int4*)&rank[base];
    int4 s4 = *(const int4*)&src[base];
    csr[off[d4.x] + aux[d4.x >> 8] + r4.x] = s4.x;
    csr[off[d4.y] + aux[d4.y >> 8] + r4.y] = s4.y;
    csr[off[d4.z] + aux[d4.z >> 8] + r4.z] = s4.z;
    csr[off[d4.w] + aux[d4.w >> 8] + r4.w] = s4.w;
}

// ---------- pack W + Wout -> MFMA B-fragment order, bf16 ----------
__global__ void k_pack(const float* __restrict__ Ws, const float* __restrict__ Wout,
                       unsigned short* __restrict__ Wpk, unsigned short* __restrict__ Wopk) {
    int t = blockIdx.x * 256 + threadIdx.x;
    if (t < NL * 16384) {
        int l = t >> 14, r = t & 16383;
        int ks = r >> 12, ct = (r >> 9) & 7, lane = (r >> 3) & 63, i = r & 7;
        int k = ks * 32 + (lane >> 4) * 8 + i;
        int n = ct * 16 + (lane & 15);
        Wpk[t] = f2bf(Ws[l * 16384 + k * 128 + n]);
    } else if (t < NL * 16384 + 8192) {
        int r = t - NL * 16384;
        int ks = r >> 11, ct = (r >> 9) & 3, lane = (r >> 3) & 63, i = r & 7;
        int k = ks * 32 + (lane >> 4) * 8 + i;
        int n = ct * 16 + (lane & 15);
        Wopk[r] = f2bf(Wout[k * 64 + n]);
    }
}

// ---------- layer-0 GEMM: Hd(bf16) = (x_f32 @ W0) * dinv ----------
__global__ __launch_bounds__(256) void k_fg0(const float* __restrict__ X,
                                             const unsigned short* __restrict__ Wpk,
                                             const float* __restrict__ dinv,
                                             unsigned short* __restrict__ Hd) {
    int w = threadIdx.x >> 6, l = threadIdx.x & 63;
    int row0 = blockIdx.x * 64 + w * 16;
    int lo = l & 15, hi = l >> 4;
    int arow = row0 + lo;
    int crow = (arow < NN) ? arow : NN - 1;
    short8 frag[4];
#pragma unroll
    for (int g = 0; g < 4; g++) {
        int cs = g * 32 + hi * 8;
        float4 p0 = *(const float4*)&X[(size_t)crow * NH + cs];
        float4 p1 = *(const float4*)&X[(size_t)crow * NH + cs + 4];
        short8 f;
        f[0] = (short)f2bf(p0.x); f[1] = (short)f2bf(p0.y);
        f[2] = (short)f2bf(p0.z); f[3] = (short)f2bf(p0.w);
        f[4] = (short)f2bf(p1.x); f[5] = (short)f2bf(p1.y);
        f[6] = (short)f2bf(p1.z); f[7] = (short)f2bf(p1.w);
        frag[g] = f;
    }
    const short8* Wv = (const short8*)Wpk;
    int srow = row0 + hi * 4;
    float dv[4];
#pragma unroll
    for (int r = 0; r < 4; r++) dv[r] = (srow + r < NN) ? dinv[srow + r] : 0.0f;
#pragma unroll
    for (int ct = 0; ct < 8; ct++) {
        f32x4 acc = {0.0f, 0.0f, 0.0f, 0.0f};
#pragma unroll
        for (int g = 0; g < 4; g++)
            acc = __builtin_amdgcn_mfma_f32_16x16x32_bf16(frag[g], Wv[(g * 8 + ct) * 64 + l], acc, 0, 0, 0);
        int col = ct * 16 + lo;
#pragma unroll
        for (int r = 0; r < 4; r++) {
            int grow = srow + r;
            if (grow < NN) Hd[grow * NH + col] = f2bf(acc[r] * dv[r]);
        }
    }
}

// ---------- fused: x_l = BN+ReLU+res(AGG,prev); Hd = (x_l @ W) * dinv ----------
__global__ __launch_bounds__(256) void k_fg(const unsigned short* __restrict__ AGGb,
                                            const float* __restrict__ scale,
                                            const float* __restrict__ shift,
                                            const float* __restrict__ Xprev,
                                            float* __restrict__ Xout,
                                            const unsigned short* __restrict__ Wpk,
                                            const float* __restrict__ dinv,
                                            unsigned short* __restrict__ Hd) {
    int w = threadIdx.x >> 6, l = threadIdx.x & 63;
    int row0 = blockIdx.x * 64 + w * 16;
    int lo = l & 15, hi = l >> 4;
    int arow = row0 + lo;
    bool valid = arow < NN;
    int crow = valid ? arow : NN - 1;
    short8 frag[4];
#pragma unroll
    for (int g = 0; g < 4; g++) {
        int cs = g * 32 + hi * 8;
        uint4 ab = *(const uint4*)&AGGb[(size_t)crow * NH + cs];
        float4 p0 = *(const float4*)&Xprev[(size_t)crow * NH + cs];
        float4 p1 = *(const float4*)&Xprev[(size_t)crow * NH + cs + 4];
        float4 sc0 = *(const float4*)&scale[cs];
        float4 sc1 = *(const float4*)&scale[cs + 4];
        float4 sh0 = *(const float4*)&shift[cs];
        float4 sh1 = *(const float4*)&shift[cs + 4];
        float o0 = fmaxf(fmaf(bflo(ab.x), sc0.x, sh0.x), 0.0f) + p0.x;
        float o1 = fmaxf(fmaf(bfhi(ab.x), sc0.y, sh0.y), 0.0f) + p0.y;
        float o2 = fmaxf(fmaf(bflo(ab.y), sc0.z, sh0.z), 0.0f) + p0.z;
        float o3 = fmaxf(fmaf(bfhi(ab.y), sc0.w, sh0.w), 0.0f) + p0.w;
        float o4 = fmaxf(fmaf(bflo(ab.z), sc1.x, sh1.x), 0.0f) + p1.x;
        float o5 = fmaxf(fmaf(bfhi(ab.z), sc1.y, sh1.y), 0.0f) + p1.y;
        float o6 = fmaxf(fmaf(bflo(ab.w), sc1.z, sh1.z), 0.0f) + p1.z;
        float o7 = fmaxf(fmaf(bfhi(ab.w), sc1.w, sh1.w), 0.0f) + p1.w;
        if (valid) {
            float4 s0 = {o0, o1, o2, o3}, s1 = {o4, o5, o6, o7};
            *(float4*)&Xout[(size_t)arow * NH + cs] = s0;
            *(float4*)&Xout[(size_t)arow * NH + cs + 4] = s1;
        }
        short8 f;
        f[0] = (short)f2bf(o0); f[1] = (short)f2bf(o1);
        f[2] = (short)f2bf(o2); f[3] = (short)f2bf(o3);
        f[4] = (short)f2bf(o4); f[5] = (short)f2bf(o5);
        f[6] = (short)f2bf(o6); f[7] = (short)f2bf(o7);
        frag[g] = f;
    }
    const short8* Wv = (const short8*)Wpk;
    int srow = row0 + hi * 4;
    float dv[4];
#pragma unroll
    for (int r = 0; r < 4; r++) dv[r] = (srow + r < NN) ? dinv[srow + r] : 0.0f;
#pragma unroll
    for (int ct = 0; ct < 8; ct++) {
        f32x4 acc = {0.0f, 0.0f, 0.0f, 0.0f};
#pragma unroll
        for (int g = 0; g < 4; g++)
            acc = __builtin_amdgcn_mfma_f32_16x16x32_bf16(frag[g], Wv[(g * 8 + ct) * 64 + l], acc, 0, 0, 0);
        int col = ct * 16 + lo;
#pragma unroll
        for (int r = 0; r < 4; r++) {
            int grow = srow + r;
            if (grow < NN) Hd[grow * NH + col] = f2bf(acc[r] * dv[r]);
        }
    }
}

// ---------- fused final: x_4 = BN+ReLU+res; out = x_4 @ Wout + bout ----------
__global__ __launch_bounds__(256) void k_fgout(const unsigned short* __restrict__ AGGb,
                                               const float* __restrict__ scale,
                                               const float* __restrict__ shift,
                                               const float* __restrict__ Xprev,
                                               const unsigned short* __restrict__ Wpk,
                                               const float* __restrict__ b,
                                               float* __restrict__ out) {
    int w = threadIdx.x >> 6, l = threadIdx.x & 63;
    int row0 = blockIdx.x * 64 + w * 16;
    int lo = l & 15, hi = l >> 4;
    int arow = row0 + lo;
    int crow = (arow < NN) ? arow : NN - 1;
    short8 frag[4];
#pragma unroll
    for (int g = 0; g < 4; g++) {
        int cs = g * 32 + hi * 8;
        uint4 ab = *(const uint4*)&AGGb[(size_t)crow * NH + cs];
        float4 p0 = *(const float4*)&Xprev[(size_t)crow * NH + cs];
        float4 p1 = *(const float4*)&Xprev[(size_t)crow * NH + cs + 4];
        float4 sc0 = *(const float4*)&scale[cs];
        float4 sc1 = *(const float4*)&scale[cs + 4];
        float4 sh0 = *(const float4*)&shift[cs];
        float4 sh1 = *(const float4*)&shift[cs + 4];
        short8 f;
        f[0] = (short)f2bf(fmaxf(fmaf(bflo(ab.x), sc0.x, sh0.x), 0.0f) + p0.x);
        f[1] = (short)f2bf(fmaxf(fmaf(bfhi(ab.x), sc0.y, sh0.y), 0.0f) + p0.y);
        f[2] = (short)f2bf(fmaxf(fmaf(bflo(ab.y), sc0.z, sh0.z), 0.0f) + p0.z);
        f[3] = (short)f2bf(fmaxf(fmaf(bfhi(ab.y), sc0.w, sh0.w), 0.0f) + p0.w);
        f[4] = (short)f2bf(fmaxf(fmaf(bflo(ab.z), sc1.x, sh1.x), 0.0f) + p1.x);
        f[5] = (short)f2bf(fmaxf(fmaf(bfhi(ab.z), sc1.y, sh1.y), 0.0f) + p1.y);
        f[6] = (short)f2bf(fmaxf(fmaf(bflo(ab.w), sc1.z, sh1.z), 0.0f) + p1.z);
        f[7] = (short)f2bf(fmaxf(fmaf(bfhi(ab.w), sc1.w, sh1.w), 0.0f) + p1.w);
        frag[g] = f;
    }
    const short8* Wv = (const short8*)Wpk;
    int srow = row0 + hi * 4;
#pragma unroll
    for (int ct = 0; ct < 4; ct++) {
        f32x4 acc = {0.0f, 0.0f, 0.0f, 0.0f};
#pragma unroll
        for (int g = 0; g < 4; g++)
            acc = __builtin_amdgcn_mfma_f32_16x16x32_bf16(frag[g], Wv[(g * 4 + ct) * 64 + l], acc, 0, 0, 0);
        int col = ct * 16 + lo;
        float bb = b[col];
#pragma unroll
        for (int r = 0; r < 4; r++) {
            int grow = srow + r;
            if (grow < NN) out[grow * NO + col] = acc[r] + bb;
        }
    }
}

// ---------- CSR gather + fused BN partial stats ----------
// 16 nodes/block, 16 threads/node. Writes AGGb + per-block column sums/sumsq.
__global__ __launch_bounds__(256) void k_gather(const unsigned short* __restrict__ Hd,
                                                const int* __restrict__ csr,
                                                const int* __restrict__ off,
                                                const int* __restrict__ aux,
                                                const int* __restrict__ deg,
                                                const float* __restrict__ dinv,
                                                unsigned short* __restrict__ AGGb,
                                                float* __restrict__ partial) {
    int b = blockIdx.x;
    int slot = threadIdx.x >> 4, q = threadIdx.x & 15;
    int g = b * 16 + slot;
    float a0 = 0, a1 = 0, a2 = 0, a3 = 0, a4 = 0, a5 = 0, a6 = 0, a7 = 0;
    if (g < NN) {
        const uint4* Hv = (const uint4*)Hd;
        int o = off[g] + aux[g >> 8];
        int d = deg[g];
        uint4 h = Hv[g * 16 + q];  // self term
        a0 = bflo(h.x); a1 = bfhi(h.x);
        a2 = bflo(h.y); a3 = bfhi(h.y);
        a4 = bflo(h.z); a5 = bfhi(h.z);
        a6 = bflo(h.w); a7 = bfhi(h.w);
        int j = 0;
        for (; j + 4 <= d; j += 4) {
            int s0 = csr[o + j], s1 = csr[o + j + 1];
            int s2 = csr[o + j + 2], s3 = csr[o + j + 3];
            uint4 h0 = Hv[s0 * 16 + q];
            uint4 h1 = Hv[s1 * 16 + q];
            uint4 h2 = Hv[s2 * 16 + q];
            uint4 h3 = Hv[s3 * 16 + q];
            a0 += (bflo(h0.x) + bflo(h1.x)) + (bflo(h2.x) + bflo(h3.x));
            a1 += (bfhi(h0.x) + bfhi(h1.x)) + (bfhi(h2.x) + bfhi(h3.x));
            a2 += (bflo(h0.y) + bflo(h1.y)) + (bflo(h2.y) + bflo(h3.y));
            a3 += (bfhi(h0.y) + bfhi(h1.y)) + (bfhi(h2.y) + bfhi(h3.y));
            a4 += (bflo(h0.z) + bflo(h1.z)) + (bflo(h2.z) + bflo(h3.z));
            a5 += (bfhi(h0.z) + bfhi(h1.z)) + (bfhi(h2.z) + bfhi(h3.z));
            a6 += (bflo(h0.w) + bflo(h1.w)) + (bflo(h2.w) + bflo(h3.w));
            a7 += (bfhi(h0.w) + bfhi(h1.w)) + (bfhi(h2.w) + bfhi(h3.w));
        }
        for (; j < d; j++) {
            int s0 = csr[o + j];
            uint4 h0 = Hv[s0 * 16 + q];
            a0 += bflo(h0.x); a1 += bfhi(h0.x);
            a2 += bflo(h0.y); a3 += bfhi(h0.y);
            a4 += bflo(h0.z); a5 += bfhi(h0.z);
            a6 += bflo(h0.w); a7 += bfhi(h0.w);
        }
        float dv = dinv[g];
        a0 *= dv; a1 *= dv; a2 *= dv; a3 *= dv;
        a4 *= dv; a5 *= dv; a6 *= dv; a7 *= dv;
        uint4 u;
        u.x = pk(a0, a1); u.y = pk(a2, a3);
        u.z = pk(a4, a5); u.w = pk(a6, a7);
        ((uint4*)AGGb)[g * 16 + q] = u;
    }
    // ---- fused BN partial stats: reduce across 16 node slots ----
    float t0 = a0 * a0, t1 = a1 * a1, t2 = a2 * a2, t3 = a3 * a3;
    float t4 = a4 * a4, t5 = a5 * a5, t6 = a6 * a6, t7 = a7 * a7;
#define RED(v) v += __shfl_xor(v, 16); v += __shfl_xor(v, 32);
    RED(a0) RED(a1) RED(a2) RED(a3) RED(a4) RED(a5) RED(a6) RED(a7)
    RED(t0) RED(t1) RED(t2) RED(t3) RED(t4) RED(t5) RED(t6) RED(t7)
#undef RED
    __shared__ float ws[4][16][16];
    int wv = threadIdx.x >> 6, lane = threadIdx.x & 63;
    if (lane < 16) {
        ws[wv][lane][0] = a0; ws[wv][lane][1] = a1;
        ws[wv][lane][2] = a2; ws[wv][lane][3] = a3;
        ws[wv][lane][4] = a4; ws[wv][lane][5] = a5;
        ws[wv][lane][6] = a6; ws[wv][lane][7] = a7;
        ws[wv][lane][8] = t0; ws[wv][lane][9] = t1;
        ws[wv][lane][10] = t2; ws[wv][lane][11] = t3;
        ws[wv][lane][12] = t4; ws[wv][lane][13] = t5;
        ws[wv][lane][14] = t6; ws[wv][lane][15] = t7;
    }
    __syncthreads();
    if (threadIdx.x < 16) {
        int qq = threadIdx.x;
#pragma unroll
        for (int k = 0; k < 8; k++) {
            float sv = ws[0][qq][k] + ws[1][qq][k] + ws[2][qq][k] + ws[3][qq][k];
            float qv = ws[0][qq][k + 8] + ws[1][qq][k + 8] + ws[2][qq][k + 8] + ws[3][qq][k + 8];
            partial[(size_t)b * 256 + qq * 8 + k] = sv;
            partial[(size_t)b * 256 + 128 + qq * 8 + k] = qv;
        }
    }
}

// ---------- reduce partials -> scale/shift (folds bn_fin) ----------
__global__ __launch_bounds__(256) void k_statred(const float* __restrict__ partial,
                                                 const float* __restrict__ gamma,
                                                 const float* __restrict__ beta,
                                                 float* __restrict__ scale,
                                                 float* __restrict__ shift) {
    int s = blockIdx.x;   // column 0..127
    int t = threadIdx.x;
    float sum = 0.0f, sq = 0.0f;
    for (int k = t; k < NGB; k += 256) {
        sum += partial[(size_t)k * 256 + s];
        sq  += partial[(size_t)k * 256 + 128 + s];
    }
    __shared__ float ls[256], lq[256];
    ls[t] = sum; lq[t] = sq;
    __syncthreads();
    for (int st = 128; st > 0; st >>= 1) {
        if (t < st) { ls[t] += ls[t + st]; lq[t] += lq[t + st]; }
        __syncthreads();
    }
    if (t == 0) {
        float mean = ls[0] * (1.0f / NN);
        float var = lq[0] * (1.0f / NN) - mean * mean;
        float istd = rsqrtf(var + BN_EPS);
        float sc = istd * gamma[s];
        scale[s] = sc;
        shift[s] = beta[s] - mean * sc;
    }
}

extern "C" void kernel_launch(void* const* d_in, const int* in_sizes, int n_in,
                              void* d_out, int out_size, void* d_ws, size_t ws_size,
                              hipStream_t stream) {
    const float* x    = (const float*)d_in[0];
    const int*   ei   = (const int*)d_in[1];
    const float* Ws   = (const float*)d_in[2];
    const float* gam  = (const float*)d_in[4];
    const float* bet  = (const float*)d_in[5];
    const float* Wout = (const float*)d_in[6];
    const float* bout = (const float*)d_in[7];
    float* out = (float*)d_out;

    const int* src = ei;
    const int* dst = ei + NE;

    char* p = (char*)d_ws;
    auto alloc = [&](size_t bytes) { char* r = p; p += (bytes + 255) & ~(size_t)255; return r; };
    int*   deg_i = (int*)alloc(NN * 4);
    int*   off   = (int*)alloc(NN * 4);
    int*   rank  = (int*)alloc((size_t)NE * 4);
    int*   aux   = (int*)alloc(256 * 4);
    int*   csr   = (int*)alloc((size_t)NE * 4);
    float* dinv  = (float*)alloc(NN * 4);
    float* XA    = (float*)alloc((size_t)NN * NH * 4);
    float* XB    = (float*)alloc((size_t)NN * NH * 4);
    unsigned short* Hd   = (unsigned short*)alloc((size_t)NN * NH * 2);
    unsigned short* AGGb = (unsigned short*)alloc((size_t)NN * NH * 2);
    unsigned short* Wpk  = (unsigned short*)alloc((size_t)NL * NH * NH * 2);
    unsigned short* Wopk = (unsigned short*)alloc((size_t)NH * NO * 2);
    float* partial = (float*)alloc((size_t)NGB * 256 * 4);   // 3.2MB
    float* scale = (float*)alloc(NH * 4);
    float* shift = (float*)alloc(NH * 4);

    // ---- preprocessing ----
    hipMemsetAsync(deg_i, 0, NN * 4, stream);
    k_degrank<<<(NE / 2 + 255) / 256, 256, 0, stream>>>(dst, deg_i, rank);
    k_scan1<<<NB1, 256, 0, stream>>>(deg_i, off, aux, dinv);
    k_scan2<<<1, 256, 0, stream>>>(aux);
    k_fill<<<(NE / 4 + 255) / 256, 256, 0, stream>>>(src, dst, off, aux, rank, csr);
    k_pack<<<(NL * 16384 + 8192 + 255) / 256, 256, 0, stream>>>(Ws, Wout, Wpk, Wopk);

    const int GB = (NN + 63) / 64;

    // ---- layer 0 GEMM from f32 input ----
    k_fg0<<<GB, 256, 0, stream>>>(x, Wpk, dinv, Hd);

    const float* xprev = x;
    for (int l = 0; l < NL; l++) {
        k_gather<<<NGB, 256, 0, stream>>>(Hd, csr, off, aux, deg_i, dinv, AGGb, partial);
        k_statred<<<128, 256, 0, stream>>>(partial, gam + l * NH, bet + l * NH, scale, shift);
        if (l < NL - 1) {
            float* Xout = (l & 1) ? XB : XA;
            k_fg<<<GB, 256, 0, stream>>>(AGGb, scale, shift, xprev, Xout,
                                         Wpk + (size_t)(l + 1) * 16384, dinv, Hd);
            xprev = Xout;
        } else {
            k_fgout<<<GB, 256, 0, stream>>>(AGGb, scale, shift, xprev, Wopk, bout, out);
        }
    }
}